// Round 1
// baseline (1047.592 us; speedup 1.0000x reference)
//
#include <hip/hip_runtime.h>
#include <cstddef>

#define NN 1000
#define NE 8000
#define FIN 64
#define DH 128
#define RD 64
#define FEPS 1e-5f

__device__ __forceinline__ float lrelu(float x){ return x > 0.f ? x : 0.01f*x; }

// ---------------- topology prep ----------------

__global__ void k_count(const int* __restrict__ src, const int* __restrict__ dst,
                        int* deg_o, int* deg_i){
  int e = blockIdx.x*blockDim.x + threadIdx.x;
  if (e < NE){ atomicAdd(&deg_o[src[e]], 1); atomicAdd(&deg_i[dst[e]], 1); }
}

__global__ void k_prep(const int* __restrict__ deg_o, const int* __restrict__ deg_i,
                       float* n_out, float* n_in, int* rp){
  __shared__ int s[1024];
  int t = threadIdx.x;
  int d = (t < NN) ? deg_i[t] : 0;
  s[t] = d; __syncthreads();
  for (int off = 1; off < 1024; off <<= 1){
    int v = (t >= off) ? s[t-off] : 0;
    __syncthreads();
    s[t] += v;
    __syncthreads();
  }
  if (t < NN){
    rp[t] = s[t] - d;                       // exclusive scan
    n_in[t]  = rsqrtf((float)max(deg_i[t], 1));
    n_out[t] = rsqrtf((float)max(deg_o[t], 1));
  }
  if (t == NN-1) rp[NN] = s[t];
}

__global__ void k_fill(const int* __restrict__ src, const int* __restrict__ dst,
                       const int* __restrict__ rp, int* fill,
                       int* csr_s, int* csr_e){
  int e = blockIdx.x*blockDim.x + threadIdx.x;
  if (e < NE){
    int dn = dst[e];
    int slot = atomicAdd(&fill[dn], 1);
    int pos = rp[dn] + slot;
    csr_s[pos] = src[e];
    csr_e[pos] = e;
  }
}

// ---------------- edge gather (one wave per node) ----------------

template<int DIN>
__global__ void k_gather(const float* __restrict__ hin, const float* __restrict__ ew,
                         const float* __restrict__ sup, const float* __restrict__ n_out,
                         const float* __restrict__ n_in, const int* __restrict__ rp,
                         const int* __restrict__ csr_s, const int* __restrict__ csr_e,
                         float* __restrict__ agg){
  int wave = threadIdx.x >> 6;
  int lane = threadIdx.x & 63;
  int b = blockIdx.x / 250;
  int v = (blockIdx.x % 250)*4 + wave;
  int kb = rp[v], ke = rp[v+1];
  float acc0 = 0.f, acc1 = 0.f;
  const float* ewb = ew + (size_t)b*NE;
  const float* hb  = hin + (size_t)b*NN*DIN;
  for (int k = kb; k < ke; ++k){
    int s = csr_s[k]; int e = csr_e[k];
    float wgt = ewb[e]*sup[e]*n_out[s];
    const float* hr = hb + (size_t)s*DIN;
    acc0 += hr[lane]*wgt;
    if (DIN == 128) acc1 += hr[lane+64]*wgt;
  }
  float sc = n_in[v];
  float* o = agg + ((size_t)b*NN + v)*DIN;
  o[lane] = acc0*sc;
  if (DIN == 128) o[lane+64] = acc1*sc;
}

// ---------------- fp32 tiled GEMM: (M x K) @ (K x 128) ----------------

template<int K>
__global__ __launch_bounds__(256) void k_gemm(const float* __restrict__ A,
                        const float* __restrict__ Wm, float* __restrict__ C){
  __shared__ float As[64*K];
  __shared__ float Ws[K*128];
  int t = threadIdx.x;
  size_t row0 = (size_t)blockIdx.x * 64;
  const float4* Asrc = (const float4*)(A + row0*K);
  float4* Ad = (float4*)As;
  #pragma unroll
  for (int i = t; i < 64*K/4; i += 256) Ad[i] = Asrc[i];
  const float4* Wsrc = (const float4*)Wm;
  float4* Wd = (float4*)Ws;
  #pragma unroll
  for (int i = t; i < K*128/4; i += 256) Wd[i] = Wsrc[i];
  __syncthreads();
  int c  = (t & 31)*4;
  int rb = (t >> 5)*8;
  float acc[8][4];
  #pragma unroll
  for (int j=0;j<8;++j){ acc[j][0]=0.f; acc[j][1]=0.f; acc[j][2]=0.f; acc[j][3]=0.f; }
  for (int k=0;k<K;++k){
    float4 w4 = *(const float4*)(Ws + k*128 + c);
    #pragma unroll
    for (int j=0;j<8;++j){
      float a = As[(rb+j)*K + k];
      acc[j][0] += a*w4.x; acc[j][1] += a*w4.y; acc[j][2] += a*w4.z; acc[j][3] += a*w4.w;
    }
  }
  #pragma unroll
  for (int j=0;j<8;++j){
    *(float4*)(C + (row0 + rb + j)*128 + c)
        = make_float4(acc[j][0],acc[j][1],acc[j][2],acc[j][3]);
  }
}

// ---------------- GraphNorm ----------------

__global__ void k_stats(const float* __restrict__ h, float* ssum, float* ssq){
  int b  = blockIdx.x >> 3;
  int ch = blockIdx.x & 7;
  int t  = threadIdx.x; // 128
  float s = 0.f, q = 0.f;
  const float* hb = h + ((size_t)b*NN + (size_t)ch*125)*DH;
  for (int v=0; v<125; ++v){
    float x = hb[(size_t)v*DH + t];
    s += x; q += x*x;
  }
  atomicAdd(&ssum[b*DH + t], s);
  atomicAdd(&ssq [b*DH + t], q);
}

__global__ void k_finstats(const float* __restrict__ ssum, const float* __restrict__ ssq,
                           const float* __restrict__ alpha,
                           float* mean, float* inv, int BD){
  int i = blockIdx.x*blockDim.x + threadIdx.x;
  if (i < BD){
    int d = i & (DH-1);
    float m   = ssum[i] * (1.f/NN);
    float ex2 = ssq [i] * (1.f/NN);
    float a = alpha[d];
    float var = ex2 - (2.f*a - a*a)*m*m;
    mean[i] = m;
    inv [i] = rsqrtf(var + FEPS);
  }
}

__global__ void k_norm(float* __restrict__ h, const float* __restrict__ mean,
                       const float* __restrict__ inv, const float* __restrict__ gamma,
                       const float* __restrict__ beta, const float* __restrict__ alpha,
                       size_t n4){
  size_t i = (size_t)blockIdx.x*blockDim.x + threadIdx.x;
  if (i >= n4) return;
  size_t e0 = i*4;
  int d = (int)(e0 & (size_t)(DH-1));
  size_t b = e0 / ((size_t)NN*DH);
  size_t bd = b*DH + d;
  float4 x  = *(float4*)(h + e0);
  float4 g  = *(const float4*)(gamma + d);
  float4 bt = *(const float4*)(beta + d);
  float4 al = *(const float4*)(alpha + d);
  float4 m  = *(const float4*)(mean + bd);
  float4 iv = *(const float4*)(inv + bd);
  x.x = lrelu(g.x*(x.x - al.x*m.x)*iv.x + bt.x);
  x.y = lrelu(g.y*(x.y - al.y*m.y)*iv.y + bt.y);
  x.z = lrelu(g.z*(x.z - al.z*m.z)*iv.z + bt.z);
  x.w = lrelu(g.w*(x.w - al.w*m.w)*iv.w + bt.w);
  *(float4*)(h + e0) = x;
}

// ---------------- UniversalReadout phi: h@phiW, lrelu, sum over nodes ----------------

__global__ __launch_bounds__(256) void k_phi(const float* __restrict__ h,
                      const float* __restrict__ Wm, const float* __restrict__ bias,
                      float* __restrict__ z, int B){
  __shared__ float As[64*128];
  __shared__ float Ws[128*128];
  __shared__ float red[8][128];
  int t = threadIdx.x;
  int b = blockIdx.x >> 4;
  int tile = blockIdx.x & 15;
  int vrow0 = tile*64;
  size_t row0 = (size_t)b*NN + vrow0;
  size_t M = (size_t)B*NN;
  for (int i = t; i < 64*128/4; i += 256){
    int r = (i*4) >> 7;
    size_t gr = row0 + r;
    if (gr > M-1) gr = M-1;
    int col = (i*4) & 127;
    *(float4*)(As + i*4) = *(const float4*)(h + gr*128 + col);
  }
  for (int i = t; i < 128*128/4; i += 256)
    ((float4*)Ws)[i] = ((const float4*)Wm)[i];
  __syncthreads();
  int c  = (t & 31)*4;
  int rb = (t >> 5)*8;
  float acc[8][4];
  #pragma unroll
  for (int j=0;j<8;++j){ acc[j][0]=0.f; acc[j][1]=0.f; acc[j][2]=0.f; acc[j][3]=0.f; }
  for (int k=0;k<128;++k){
    float4 w4 = *(const float4*)(Ws + k*128 + c);
    #pragma unroll
    for (int j=0;j<8;++j){
      float a = As[(rb+j)*128 + k];
      acc[j][0] += a*w4.x; acc[j][1] += a*w4.y; acc[j][2] += a*w4.z; acc[j][3] += a*w4.w;
    }
  }
  float4 bi = *(const float4*)(bias + c);
  float cs0=0.f, cs1=0.f, cs2=0.f, cs3=0.f;
  #pragma unroll
  for (int j=0;j<8;++j){
    if (vrow0 + rb + j < NN){
      cs0 += lrelu(acc[j][0] + bi.x);
      cs1 += lrelu(acc[j][1] + bi.y);
      cs2 += lrelu(acc[j][2] + bi.z);
      cs3 += lrelu(acc[j][3] + bi.w);
    }
  }
  red[t>>5][c]   = cs0;
  red[t>>5][c+1] = cs1;
  red[t>>5][c+2] = cs2;
  red[t>>5][c+3] = cs3;
  __syncthreads();
  if (t < 128){
    float s = 0.f;
    #pragma unroll
    for (int g=0; g<8; ++g) s += red[g][t];
    atomicAdd(&z[b*128 + t], s);
  }
}

__global__ void k_rho(const float* __restrict__ z, const float* __restrict__ Wm,
                      const float* __restrict__ bias, float* __restrict__ out, int off){
  int b = blockIdx.x;
  int d = threadIdx.x; // 64
  float acc = bias[d];
  const float* zb = z + b*128;
  for (int k=0;k<128;++k) acc += zb[k]*Wm[k*64 + d];
  out[(size_t)b*640 + off + d] = lrelu(acc);
}

// ---------------- weighted mean readout ----------------

template<int DIN>
__global__ void k_wmean(const float* __restrict__ h, const float* __restrict__ gw,
                        const float* __restrict__ ar, float* __restrict__ out, int off){
  int b  = blockIdx.x >> 3;
  int ch = blockIdx.x & 7;
  int t  = threadIdx.x; // DIN
  float acc = 0.f;
  const float* hb  = h + ((size_t)b*NN + (size_t)ch*125)*DIN;
  const float* gwb = gw + (size_t)b*NN + (size_t)ch*125;
  const float* arb = ar + ch*125;
  for (int v=0; v<125; ++v){
    acc += gwb[v]*arb[v]*hb[(size_t)v*DIN + t];
  }
  atomicAdd(&out[(size_t)b*640 + off + t], acc*(1.f/NN));
}

__global__ void k_flrelu(float* o, int n){
  int i = blockIdx.x*blockDim.x + threadIdx.x;
  if (i < n) o[i] = lrelu(o[i]);
}

// ---------------- launcher ----------------

extern "C" void kernel_launch(void* const* d_in, const int* in_sizes, int n_in,
                              void* d_out, int out_size, void* d_ws, size_t ws_size,
                              hipStream_t stream){
  const float* x    = (const float*)d_in[0];
  const float* ew   = (const float*)d_in[1];
  const float* gw   = (const float*)d_in[2];
  const float* W1   = (const float*)d_in[3];
  const float* W2   = (const float*)d_in[4];
  const float* W3   = (const float*)d_in[5];
  const float* sup  = (const float*)d_in[6];
  const float* AR   = (const float*)d_in[7];
  const float* gam  = (const float*)d_in[8];
  const float* bet  = (const float*)d_in[9];
  const float* alp  = (const float*)d_in[10];
  const float* phiW = (const float*)d_in[11];
  const float* phib = (const float*)d_in[12];
  const float* rhoW = (const float*)d_in[13];
  const float* rhob = (const float*)d_in[14];
  const int*   src  = (const int*)d_in[15];
  const int*   dst  = (const int*)d_in[16];
  float* out = (float*)d_out;

  int B = in_sizes[0] / (NN*FIN);
  size_t M = (size_t)B*NN;

  float* w = (float*)d_ws;
  size_t p = 0;
  int* deg_o = (int*)(w+p); p += 1024;
  int* deg_i = (int*)(w+p); p += 1024;
  int* fillc = (int*)(w+p); p += 1024;
  float* ssum = w+p; p += (size_t)B*DH;
  float* ssq  = w+p; p += (size_t)B*DH;
  float* zbuf = w+p; p += (size_t)B*DH;
  float* nout = w+p; p += 1024;
  float* nin  = w+p; p += 1024;
  int* rp     = (int*)(w+p); p += 1024;
  int* csr_s  = (int*)(w+p); p += NE;
  int* csr_e  = (int*)(w+p); p += NE;
  float* mean = w+p; p += (size_t)B*DH;
  float* inv  = w+p; p += (size_t)B*DH;
  float* hA   = w+p; p += M*DH;
  float* hB   = w+p; p += M*DH;

  // zero: deg_o/deg_i/fill contiguous; out
  hipMemsetAsync(deg_o, 0, 3*1024*sizeof(int), stream);
  hipMemsetAsync(out, 0, (size_t)out_size*sizeof(float), stream);

  k_count<<<(NE+255)/256, 256, 0, stream>>>(src, dst, deg_o, deg_i);
  k_prep <<<1, 1024, 0, stream>>>(deg_o, deg_i, nout, nin, rp);
  k_fill <<<(NE+255)/256, 256, 0, stream>>>(src, dst, rp, fillc, csr_s, csr_e);

  // piece 0: weighted mean of raw x with AR[0]
  k_wmean<FIN><<<B*8, FIN, 0, stream>>>(x, gw, AR, out, 0);

  const float* Ws_[3] = {W1, W2, W3};
  const int off_uro[3] = {64, 256, 448};
  const int off_wm [3] = {128, 320, 512};

  for (int i=0;i<3;++i){
    // zero ssum/ssq/z (contiguous)
    hipMemsetAsync(ssum, 0, 3*(size_t)B*DH*sizeof(float), stream);

    if (i == 0)
      k_gather<FIN><<<B*250, 256, 0, stream>>>(x,  ew, sup + (size_t)i*NE, nout, nin, rp, csr_s, csr_e, hB);
    else
      k_gather<DH> <<<B*250, 256, 0, stream>>>(hA, ew, sup + (size_t)i*NE, nout, nin, rp, csr_s, csr_e, hB);

    if (i == 0)
      k_gemm<FIN><<<(int)(M/64), 256, 0, stream>>>(hB, Ws_[i], hA);
    else
      k_gemm<DH> <<<(int)(M/64), 256, 0, stream>>>(hB, Ws_[i], hA);

    k_stats   <<<B*8, DH, 0, stream>>>(hA, ssum, ssq);
    k_finstats<<<(B*DH+255)/256, 256, 0, stream>>>(ssum, ssq, alp + i*DH, mean, inv, B*DH);

    size_t n4 = M*DH/4;
    k_norm<<<(int)((n4+255)/256), 256, 0, stream>>>(hA, mean, inv, gam + i*DH, bet + i*DH, alp + i*DH, n4);

    k_phi<<<B*16, 256, 0, stream>>>(hA, phiW + (size_t)i*DH*DH, phib + i*DH, zbuf, B);
    k_rho<<<B, RD, 0, stream>>>(zbuf, rhoW + (size_t)i*DH*RD, rhob + i*RD, out, off_uro[i]);
    k_wmean<DH><<<B*8, DH, 0, stream>>>(hA, gw, AR + (size_t)(i+1)*NN, out, off_wm[i]);
  }

  k_flrelu<<<(B*640+255)/256, 256, 0, stream>>>(out, B*640);
}

// Round 2
// 442.919 us; speedup vs baseline: 2.3652x; 2.3652x over previous
//
#include <hip/hip_runtime.h>
#include <cstddef>

#define NN 1000
#define NE 8000
#define FIN 64
#define DH 128
#define RD 64
#define FEPS 1e-5f

typedef short short8 __attribute__((ext_vector_type(8)));
typedef float f32x4 __attribute__((ext_vector_type(4)));

__device__ __forceinline__ float lrelu(float x){ return x > 0.f ? x : 0.01f*x; }

__device__ __forceinline__ unsigned short f2b(float x){
  union { float f; unsigned int u; } v; v.f = x;
  unsigned int r = (v.u + 0x7fffu + ((v.u >> 16) & 1u)) >> 16;
  return (unsigned short)r;
}
__device__ __forceinline__ float b2f(unsigned int lo16){
  union { unsigned int u; float f; } v; v.u = lo16 << 16; return v.f;
}
__device__ __forceinline__ unsigned int pack2(float a, float b){
  return (unsigned int)f2b(a) | ((unsigned int)f2b(b) << 16);
}

// ---------------- topology prep ----------------

__global__ void k_count(const int* __restrict__ src, const int* __restrict__ dst,
                        int* deg_o, int* deg_i){
  int e = blockIdx.x*blockDim.x + threadIdx.x;
  if (e < NE){ atomicAdd(&deg_o[src[e]], 1); atomicAdd(&deg_i[dst[e]], 1); }
}

__global__ void k_prep(const int* __restrict__ deg_o, const int* __restrict__ deg_i,
                       float* n_out, float* n_in, int* rp){
  __shared__ int s[1024];
  int t = threadIdx.x;
  int d = (t < NN) ? deg_i[t] : 0;
  s[t] = d; __syncthreads();
  for (int off = 1; off < 1024; off <<= 1){
    int v = (t >= off) ? s[t-off] : 0;
    __syncthreads();
    s[t] += v;
    __syncthreads();
  }
  if (t < NN){
    rp[t] = s[t] - d;
    n_in[t]  = rsqrtf((float)max(deg_i[t], 1));
    n_out[t] = rsqrtf((float)max(deg_o[t], 1));
  }
  if (t == NN-1) rp[NN] = s[t];
}

__global__ void k_fill(const int* __restrict__ src, const int* __restrict__ dst,
                       const int* __restrict__ rp, int* fill,
                       int* csr_s, int* csr_e){
  int e = blockIdx.x*blockDim.x + threadIdx.x;
  if (e < NE){
    int dn = dst[e];
    int slot = atomicAdd(&fill[dn], 1);
    int pos = rp[dn] + slot;
    csr_s[pos] = src[e];
    csr_e[pos] = e;
  }
}

// ---------------- weight prep: fp32 -> bf16, transposed to [N][K] ----------------

__global__ void k_prepw(const float* __restrict__ W1, const float* __restrict__ W2,
                        const float* __restrict__ W3, const float* __restrict__ phiW,
                        unsigned short* __restrict__ wt){
  int i = blockIdx.x*256 + threadIdx.x;
  if (i < 8192){                      // W1: 64x128 -> [128][64]
    int n = i >> 6, k = i & 63;
    wt[i] = f2b(W1[k*128 + n]);
  } else if (i < 24576){              // W2: 128x128 -> [128][128]
    int j = i - 8192; int n = j >> 7, k = j & 127;
    wt[i] = f2b(W2[k*128 + n]);
  } else if (i < 40960){              // W3
    int j = i - 24576; int n = j >> 7, k = j & 127;
    wt[i] = f2b(W3[k*128 + n]);
  } else if (i < 90112){              // phiW[3]
    int j = i - 40960; int m = j >> 14; int jj = j & 16383;
    int n = jj >> 7, k = jj & 127;
    wt[i] = f2b(phiW[m*16384 + k*128 + n]);
  }
}

// ---------------- edge gather (one wave per node), XCD-swizzled ----------------

__global__ void k_gath0(const float* __restrict__ x, const float* __restrict__ ew,
                        const float* __restrict__ sup, const float* __restrict__ nout,
                        const float* __restrict__ nin, const int* __restrict__ rp,
                        const int* __restrict__ csr_s, const int* __restrict__ csr_e,
                        unsigned short* __restrict__ agg){
  int nwg8 = gridDim.x >> 3;
  int lid = (blockIdx.x & 7)*nwg8 + (blockIdx.x >> 3);
  int b = lid/250, v4 = lid%250;
  int wv = threadIdx.x >> 6, l = threadIdx.x & 63;
  int v = v4*4 + wv;
  int kb = rp[v], ke = rp[v+1];
  const float* xb  = x  + (size_t)b*NN*FIN;
  const float* ewb = ew + (size_t)b*NE;
  float acc = 0.f, acc2 = 0.f;
  int k = kb;
  for (; k+1 < ke; k += 2){
    int s0 = csr_s[k],   e0 = csr_e[k];
    int s1 = csr_s[k+1], e1 = csr_e[k+1];
    float w0 = ewb[e0]*sup[e0]*nout[s0];
    float w1 = ewb[e1]*sup[e1]*nout[s1];
    acc  += xb[(size_t)s0*FIN + l]*w0;
    acc2 += xb[(size_t)s1*FIN + l]*w1;
  }
  if (k < ke){
    int s0 = csr_s[k], e0 = csr_e[k];
    acc += xb[(size_t)s0*FIN + l]*(ewb[e0]*sup[e0]*nout[s0]);
  }
  agg[((size_t)b*NN + v)*FIN + l] = f2b((acc + acc2)*nin[v]);
}

__global__ void k_gathB(const unsigned short* __restrict__ h, const float* __restrict__ ew,
                        const float* __restrict__ sup, const float* __restrict__ nout,
                        const float* __restrict__ nin, const int* __restrict__ rp,
                        const int* __restrict__ csr_s, const int* __restrict__ csr_e,
                        unsigned short* __restrict__ agg){
  int nwg8 = gridDim.x >> 3;
  int lid = (blockIdx.x & 7)*nwg8 + (blockIdx.x >> 3);
  int b = lid/250, v4 = lid%250;
  int wv = threadIdx.x >> 6, l = threadIdx.x & 63;
  int v = v4*4 + wv;
  int kb = rp[v], ke = rp[v+1];
  const unsigned short* hb = h + (size_t)b*NN*DH;
  const float* ewb = ew + (size_t)b*NE;
  float a0 = 0.f, a1 = 0.f, c0 = 0.f, c1 = 0.f;
  int k = kb;
  for (; k+1 < ke; k += 2){
    int s0 = csr_s[k],   e0 = csr_e[k];
    int s1 = csr_s[k+1], e1 = csr_e[k+1];
    float w0 = ewb[e0]*sup[e0]*nout[s0];
    float w1 = ewb[e1]*sup[e1]*nout[s1];
    unsigned int u0 = *(const unsigned int*)(hb + (size_t)s0*DH + l*2);
    unsigned int u1 = *(const unsigned int*)(hb + (size_t)s1*DH + l*2);
    a0 += b2f(u0 & 0xffffu)*w0; a1 += b2f(u0 >> 16)*w0;
    c0 += b2f(u1 & 0xffffu)*w1; c1 += b2f(u1 >> 16)*w1;
  }
  if (k < ke){
    int s0 = csr_s[k], e0 = csr_e[k];
    float w0 = ewb[e0]*sup[e0]*nout[s0];
    unsigned int u0 = *(const unsigned int*)(hb + (size_t)s0*DH + l*2);
    a0 += b2f(u0 & 0xffffu)*w0; a1 += b2f(u0 >> 16)*w0;
  }
  float sc = nin[v];
  unsigned int* o = (unsigned int*)(agg + ((size_t)b*NN + v)*DH);
  o[l] = pack2((a0 + c0)*sc, (a1 + c1)*sc);
}

// ---------------- MFMA GEMM: (64 rows of one batch) x (K) @ Wt[128][K] ----------------
// EPI=0: write C fp32 + fused GraphNorm stats atomics (red_out = ssum, ssq right after)
// EPI=1: lrelu(C + bias), sum over valid rows -> atomicAdd red_out (= z)

template<int K, int EPI>
__global__ __launch_bounds__(256) void k_mm(const unsigned short* __restrict__ A,
        const unsigned short* __restrict__ Wt, float* __restrict__ C,
        const float* __restrict__ bias, float* __restrict__ red_out, int B){
  constexpr int K2 = K*2;            // bytes per row
  constexpr int CPR = K/8;           // 16B chunks per row
  __shared__ __align__(16) char smem[64*K2 + 128*K2];
  char* sA = smem;
  char* sW = smem + 64*K2;
  int t = threadIdx.x;
  int b = blockIdx.x >> 4;
  int tile = blockIdx.x & 15;
  int rows = NN - tile*64; if (rows > 64) rows = 64;
  size_t row0 = (size_t)b*NN + tile*64;
  size_t Mtot = (size_t)B*NN;

  for (int i = t; i < 64*CPR; i += 256){
    int r = i/CPR, cb = i%CPR;
    size_t gr = row0 + r; if (gr >= Mtot) gr = Mtot - 1;
    uint4 v = *(const uint4*)(A + gr*K + cb*8);
    *(uint4*)(sA + r*K2 + ((cb*16) ^ ((r & 7) << 4))) = v;
  }
  for (int i = t; i < 128*CPR; i += 256){
    int n = i/CPR, cb = i%CPR;
    uint4 v = *(const uint4*)(Wt + n*K + cb*8);
    *(uint4*)(sW + n*K2 + ((cb*16) ^ ((n & 7) << 4))) = v;
  }
  __syncthreads();

  int w = t >> 6, l = t & 63;
  int lr = l & 15, lk = l >> 4;
  f32x4 acc[8] = {};
  int arow = w*16 + lr;
  #pragma unroll
  for (int kk = 0; kk < K/32; ++kk){
    int kb = kk*64 + lk*16;
    short8 a = *(const short8*)(sA + arow*K2 + (kb ^ ((arow & 7) << 4)));
    #pragma unroll
    for (int f = 0; f < 8; ++f){
      int n = f*16 + lr;
      short8 bf = *(const short8*)(sW + n*K2 + (kb ^ ((n & 7) << 4)));
      acc[f] = __builtin_amdgcn_mfma_f32_16x16x32_bf16(a, bf, acc[f], 0, 0, 0);
    }
  }
  __syncthreads();   // done with sA/sW; reuse as reduction buffer

  float* red = (float*)smem;   // [4][128] sums, then [4][128] sq
  float cs[8], cq[8];
  int rbase = w*16 + lk*4;
  #pragma unroll
  for (int f = 0; f < 8; ++f){
    int col = f*16 + lr;
    float bv = (EPI == 1) ? bias[col] : 0.f;
    float s = 0.f, q = 0.f;
    #pragma unroll
    for (int r = 0; r < 4; ++r){
      int row = rbase + r;
      bool ok = row < rows;
      float v = acc[f][r];
      if (EPI == 0){
        if (ok) C[(row0 + row)*DH + col] = v;
        s += ok ? v : 0.f;
        q += ok ? v*v : 0.f;
      } else {
        float u = lrelu(v + bv);
        s += ok ? u : 0.f;
      }
    }
    s += __shfl_xor(s, 16); s += __shfl_xor(s, 32);
    cs[f] = s;
    if (EPI == 0){ q += __shfl_xor(q, 16); q += __shfl_xor(q, 32); cq[f] = q; }
  }
  if (l < 16){
    #pragma unroll
    for (int f = 0; f < 8; ++f){
      red[w*128 + f*16 + l] = cs[f];
      if (EPI == 0) red[512 + w*128 + f*16 + l] = cq[f];
    }
  }
  __syncthreads();
  if (t < 128){
    float s = red[t] + red[128+t] + red[256+t] + red[384+t];
    atomicAdd(&red_out[(size_t)b*DH + t], s);
    if (EPI == 0){
      float q = red[512+t] + red[640+t] + red[768+t] + red[896+t];
      atomicAdd(&red_out[(size_t)B*DH + (size_t)b*DH + t], q);
    }
  }
}

// ---------------- GraphNorm finalize + lrelu + bf16 cast (stats inline) ----------------

__global__ void k_norm(const float* __restrict__ hC, const float* __restrict__ ssum,
                       const float* __restrict__ ssq, const float* __restrict__ gamma,
                       const float* __restrict__ beta, const float* __restrict__ alpha,
                       unsigned short* __restrict__ hbf, size_t n4){
  size_t i = (size_t)blockIdx.x*blockDim.x + threadIdx.x;
  if (i >= n4) return;
  size_t e0 = i*4;
  int d = (int)(e0 & (size_t)(DH-1));
  int b = (int)(e0 / ((size_t)NN*DH));
  const float inv_n = 1.f/NN;
  float4 x4 = *(const float4*)(hC + e0);
  float xv[4] = {x4.x, x4.y, x4.z, x4.w};
  unsigned short o[4];
  #pragma unroll
  for (int j = 0; j < 4; ++j){
    int col = b*DH + d + j;
    float m   = ssum[col]*inv_n;
    float ex2 = ssq [col]*inv_n;
    float a   = alpha[d+j];
    float var = ex2 - (2.f*a - a*a)*m*m;
    float iv  = rsqrtf(var + FEPS);
    o[j] = f2b(lrelu(gamma[d+j]*(xv[j] - a*m)*iv + beta[d+j]));
  }
  ushort4 u; u.x = o[0]; u.y = o[1]; u.z = o[2]; u.w = o[3];
  *(ushort4*)(hbf + e0) = u;
}

// ---------------- rho: z(128) @ rhoW(128x64) ----------------

__global__ void k_rho(const float* __restrict__ z, const float* __restrict__ Wm,
                      const float* __restrict__ bias, float* __restrict__ out, int off){
  int b = blockIdx.x;
  int d = threadIdx.x; // 64
  float acc = bias[d];
  const float* zb = z + b*DH;
  for (int k = 0; k < DH; ++k) acc += zb[k]*Wm[k*RD + d];
  out[(size_t)b*640 + off + d] = lrelu(acc);
}

// ---------------- weighted mean readouts ----------------

__global__ void k_wmean0(const float* __restrict__ h, const float* __restrict__ gw,
                         const float* __restrict__ ar, float* __restrict__ out, int off){
  int b = blockIdx.x >> 3, ch = blockIdx.x & 7, t = threadIdx.x; // 64
  float acc = 0.f;
  const float* hb  = h  + ((size_t)b*NN + (size_t)ch*125)*FIN;
  const float* gwb = gw + (size_t)b*NN + (size_t)ch*125;
  const float* arb = ar + ch*125;
  for (int v = 0; v < 125; ++v) acc += gwb[v]*arb[v]*hb[(size_t)v*FIN + t];
  atomicAdd(&out[(size_t)b*640 + off + t], acc*(1.f/NN));
}

__global__ void k_wmeanB(const unsigned short* __restrict__ h, const float* __restrict__ gw,
                         const float* __restrict__ ar, float* __restrict__ out, int off){
  int b = blockIdx.x >> 3, ch = blockIdx.x & 7, t = threadIdx.x; // 128
  float acc = 0.f;
  const unsigned short* hb = h + ((size_t)b*NN + (size_t)ch*125)*DH;
  const float* gwb = gw + (size_t)b*NN + (size_t)ch*125;
  const float* arb = ar + ch*125;
  for (int v = 0; v < 125; ++v) acc += gwb[v]*arb[v]*b2f(hb[(size_t)v*DH + t]);
  atomicAdd(&out[(size_t)b*640 + off + t], acc*(1.f/NN));
}

__global__ void k_flrelu(float* o, int n){
  int i = blockIdx.x*blockDim.x + threadIdx.x;
  if (i < n) o[i] = lrelu(o[i]);
}

// ---------------- launcher ----------------

extern "C" void kernel_launch(void* const* d_in, const int* in_sizes, int n_in,
                              void* d_out, int out_size, void* d_ws, size_t ws_size,
                              hipStream_t stream){
  const float* x    = (const float*)d_in[0];
  const float* ew   = (const float*)d_in[1];
  const float* gw   = (const float*)d_in[2];
  const float* W1   = (const float*)d_in[3];
  const float* W2   = (const float*)d_in[4];
  const float* W3   = (const float*)d_in[5];
  const float* sup  = (const float*)d_in[6];
  const float* AR   = (const float*)d_in[7];
  const float* gam  = (const float*)d_in[8];
  const float* bet  = (const float*)d_in[9];
  const float* alp  = (const float*)d_in[10];
  const float* phiW = (const float*)d_in[11];
  const float* phib = (const float*)d_in[12];
  const float* rhoW = (const float*)d_in[13];
  const float* rhob = (const float*)d_in[14];
  const int*   src  = (const int*)d_in[15];
  const int*   dst  = (const int*)d_in[16];
  float* out = (float*)d_out;

  int B = in_sizes[0] / (NN*FIN);
  size_t M = (size_t)B*NN;

  float* w = (float*)d_ws;
  size_t p = 0;
  int* deg_o = (int*)(w+p); p += 1024;
  int* deg_i = (int*)(w+p); p += 1024;
  int* fillc = (int*)(w+p); p += 1024;
  float* nout = w+p; p += 1024;
  float* nin  = w+p; p += 1024;
  int* rp     = (int*)(w+p); p += 1024;
  int* csr_s  = (int*)(w+p); p += 8192;
  int* csr_e  = (int*)(w+p); p += 8192;
  float* ssum = w+p; p += (size_t)B*DH;   // ssq must follow ssum (fused atomics)
  float* ssq  = w+p; p += (size_t)B*DH;
  float* zbuf = w+p; p += (size_t)B*DH;
  unsigned short* wt = (unsigned short*)(w+p); p += 45056;   // 90112 bf16
  float* hC = w+p; p += M*DH;                                 // fp32 GEMM out
  unsigned short* hbf = (unsigned short*)(w+p); p += M*DH/2;  // bf16 h
  unsigned short* agg = (unsigned short*)(w+p); p += M*DH/2;  // bf16 gathered

  hipMemsetAsync(deg_o, 0, 3*1024*sizeof(int), stream);
  hipMemsetAsync(out, 0, (size_t)out_size*sizeof(float), stream);

  k_count<<<(NE+255)/256, 256, 0, stream>>>(src, dst, deg_o, deg_i);
  k_prep <<<1, 1024, 0, stream>>>(deg_o, deg_i, nout, nin, rp);
  k_fill <<<(NE+255)/256, 256, 0, stream>>>(src, dst, rp, fillc, csr_s, csr_e);
  k_prepw<<<352, 256, 0, stream>>>(W1, W2, W3, phiW, wt);

  k_wmean0<<<B*8, FIN, 0, stream>>>(x, gw, AR, out, 0);

  const int off_uro[3] = {64, 256, 448};
  const int off_wm [3] = {128, 320, 512};
  const int wt_off [3] = {0, 8192, 24576};
  size_t n4 = M*DH/4;

  for (int i = 0; i < 3; ++i){
    hipMemsetAsync(ssum, 0, 3*(size_t)B*DH*sizeof(float), stream);

    if (i == 0){
      k_gath0<<<B*250, 256, 0, stream>>>(x, ew, sup, nout, nin, rp, csr_s, csr_e, agg);
      k_mm<FIN,0><<<B*16, 256, 0, stream>>>(agg, wt, hC, nullptr, ssum, B);
    } else {
      k_gathB<<<B*250, 256, 0, stream>>>(hbf, ew, sup + (size_t)i*NE, nout, nin, rp, csr_s, csr_e, agg);
      k_mm<DH,0><<<B*16, 256, 0, stream>>>(agg, wt + wt_off[i], hC, nullptr, ssum, B);
    }

    k_norm<<<(int)((n4+255)/256), 256, 0, stream>>>(hC, ssum, ssq, gam + i*DH, bet + i*DH, alp + i*DH, hbf, n4);

    k_mm<DH,1><<<B*16, 256, 0, stream>>>(hbf, wt + 40960 + i*16384, nullptr, phib + i*DH, zbuf, B);
    k_rho<<<B, RD, 0, stream>>>(zbuf, rhoW + (size_t)i*DH*RD, rhob + i*RD, out, off_uro[i]);
    k_wmeanB<<<B*8, DH, 0, stream>>>(hbf, gw, AR + (size_t)(i+1)*NN, out, off_wm[i]);
  }

  k_flrelu<<<(B*640+255)/256, 256, 0, stream>>>(out, B*640);
}

// Round 3
// 424.005 us; speedup vs baseline: 2.4707x; 1.0446x over previous
//
#include <hip/hip_runtime.h>
#include <cstddef>

#define NN 1000
#define NE 8000
#define FIN 64
#define DH 128
#define RD 64
#define FEPS 1e-5f

typedef short short8 __attribute__((ext_vector_type(8)));
typedef float f32x4 __attribute__((ext_vector_type(4)));

__device__ __forceinline__ float lrelu(float x){ return x > 0.f ? x : 0.01f*x; }

__device__ __forceinline__ unsigned short f2b(float x){
  union { float f; unsigned int u; } v; v.f = x;
  unsigned int r = (v.u + 0x7fffu + ((v.u >> 16) & 1u)) >> 16;
  return (unsigned short)r;
}
__device__ __forceinline__ float b2f(unsigned int lo16){
  union { unsigned int u; float f; } v; v.u = lo16 << 16; return v.f;
}
__device__ __forceinline__ unsigned int pack2(float a, float b){
  return (unsigned int)f2b(a) | ((unsigned int)f2b(b) << 16);
}

// ---------------- topology prep ----------------

__global__ void k_count(const int* __restrict__ src, const int* __restrict__ dst,
                        int* deg_o, int* deg_i){
  int e = blockIdx.x*blockDim.x + threadIdx.x;
  if (e < NE){ atomicAdd(&deg_o[src[e]], 1); atomicAdd(&deg_i[dst[e]], 1); }
}

__global__ void k_prep(const int* __restrict__ deg_o, const int* __restrict__ deg_i,
                       float* n_out, float* n_in, int* rp){
  __shared__ int s[1024];
  int t = threadIdx.x;
  int d = (t < NN) ? deg_i[t] : 0;
  s[t] = d; __syncthreads();
  for (int off = 1; off < 1024; off <<= 1){
    int v = (t >= off) ? s[t-off] : 0;
    __syncthreads();
    s[t] += v;
    __syncthreads();
  }
  if (t < NN){
    rp[t] = s[t] - d;
    n_in[t]  = rsqrtf((float)max(deg_i[t], 1));
    n_out[t] = rsqrtf((float)max(deg_o[t], 1));
  }
  if (t == NN-1) rp[NN] = s[t];
}

__global__ void k_fill(const int* __restrict__ src, const int* __restrict__ dst,
                       const int* __restrict__ rp, int* fill,
                       int* csr_s, int* csr_e, int* csr_d){
  int e = blockIdx.x*blockDim.x + threadIdx.x;
  if (e < NE){
    int dn = dst[e];
    int slot = atomicAdd(&fill[dn], 1);
    int pos = rp[dn] + slot;
    csr_s[pos] = src[e];
    csr_e[pos] = e;
    csr_d[pos] = dn;
  }
}

// combined per-(layer,batch,csr-pos) edge weight: ew*sup*nout[src]*nin[dst]
__global__ void k_wcomb(const float* __restrict__ ew, const float* __restrict__ sup,
                        const float* __restrict__ nout, const float* __restrict__ nin,
                        const int* __restrict__ csr_s, const int* __restrict__ csr_e,
                        const int* __restrict__ csr_d, float* __restrict__ wc){
  int k = blockIdx.x*blockDim.x + threadIdx.x;
  if (k >= NE) return;
  int b = blockIdx.y, i = blockIdx.z;
  int e = csr_e[k], s = csr_s[k], d = csr_d[k];
  wc[((size_t)i*gridDim.y + b)*NE + k] =
      ew[(size_t)b*NE + e]*sup[(size_t)i*NE + e]*nout[s]*nin[d];
}

// ---------------- weight prep: fp32 -> bf16, transposed to [N][K] ----------------

__global__ void k_prepw(const float* __restrict__ W1, const float* __restrict__ W2,
                        const float* __restrict__ W3, const float* __restrict__ phiW,
                        unsigned short* __restrict__ wt){
  int i = blockIdx.x*256 + threadIdx.x;
  if (i < 8192){                      // W1: 64x128 -> [128][64]
    int n = i >> 6, k = i & 63;
    wt[i] = f2b(W1[k*128 + n]);
  } else if (i < 24576){              // W2: 128x128 -> [128][128]
    int j = i - 8192; int n = j >> 7, k = j & 127;
    wt[i] = f2b(W2[k*128 + n]);
  } else if (i < 40960){              // W3
    int j = i - 24576; int n = j >> 7, k = j & 127;
    wt[i] = f2b(W3[k*128 + n]);
  } else if (i < 90112){              // phiW[3]
    int j = i - 40960; int m = j >> 14; int jj = j & 16383;
    int n = jj >> 7, k = jj & 127;
    wt[i] = f2b(phiW[m*16384 + k*128 + n]);
  }
}

// ---------------- edge gather (one wave per node), XCD-swizzled ----------------

__global__ void k_gath0(const float* __restrict__ x, const float* __restrict__ wc,
                        const int* __restrict__ rp, const int* __restrict__ csr_s,
                        unsigned short* __restrict__ agg){
  int nwg8 = gridDim.x >> 3;
  int lid = (blockIdx.x & 7)*nwg8 + (blockIdx.x >> 3);
  int b = lid/250, v4 = lid%250;
  int wv = threadIdx.x >> 6, l = threadIdx.x & 63;
  int v = v4*4 + wv;
  int kb = rp[v], ke = rp[v+1];
  const float* xb  = x + (size_t)b*NN*FIN;
  const float* wcb = wc + (size_t)b*NE;
  float a0=0.f, a1=0.f, a2=0.f, a3=0.f;
  int k = kb;
  for (; k+3 < ke; k += 4){
    int s0=csr_s[k], s1=csr_s[k+1], s2=csr_s[k+2], s3=csr_s[k+3];
    float w0=wcb[k], w1=wcb[k+1], w2=wcb[k+2], w3=wcb[k+3];
    a0 += xb[s0*FIN + l]*w0;
    a1 += xb[s1*FIN + l]*w1;
    a2 += xb[s2*FIN + l]*w2;
    a3 += xb[s3*FIN + l]*w3;
  }
  for (; k < ke; ++k){
    a0 += xb[csr_s[k]*FIN + l]*wcb[k];
  }
  agg[((size_t)b*NN + v)*FIN + l] = f2b(a0+a1+a2+a3);
}

__global__ void k_gathB(const unsigned short* __restrict__ h, const float* __restrict__ wc,
                        const int* __restrict__ rp, const int* __restrict__ csr_s,
                        unsigned short* __restrict__ agg){
  int nwg8 = gridDim.x >> 3;
  int lid = (blockIdx.x & 7)*nwg8 + (blockIdx.x >> 3);
  int b = lid/250, v4 = lid%250;
  int wv = threadIdx.x >> 6, l = threadIdx.x & 63;
  int v = v4*4 + wv;
  int kb = rp[v], ke = rp[v+1];
  const unsigned short* hb = h + (size_t)b*NN*DH;
  const float* wcb = wc + (size_t)b*NE;
  int l2 = l*2;
  float lo0=0.f,lo1=0.f,lo2=0.f,lo3=0.f, hi0=0.f,hi1=0.f,hi2=0.f,hi3=0.f;
  int k = kb;
  for (; k+3 < ke; k += 4){
    int s0=csr_s[k], s1=csr_s[k+1], s2=csr_s[k+2], s3=csr_s[k+3];
    float w0=wcb[k], w1=wcb[k+1], w2=wcb[k+2], w3=wcb[k+3];
    unsigned u0 = *(const unsigned*)(hb + s0*DH + l2);
    unsigned u1 = *(const unsigned*)(hb + s1*DH + l2);
    unsigned u2 = *(const unsigned*)(hb + s2*DH + l2);
    unsigned u3 = *(const unsigned*)(hb + s3*DH + l2);
    lo0 += b2f(u0 & 0xffffu)*w0; hi0 += b2f(u0 >> 16)*w0;
    lo1 += b2f(u1 & 0xffffu)*w1; hi1 += b2f(u1 >> 16)*w1;
    lo2 += b2f(u2 & 0xffffu)*w2; hi2 += b2f(u2 >> 16)*w2;
    lo3 += b2f(u3 & 0xffffu)*w3; hi3 += b2f(u3 >> 16)*w3;
  }
  for (; k < ke; ++k){
    int s0 = csr_s[k]; float w0 = wcb[k];
    unsigned u0 = *(const unsigned*)(hb + s0*DH + l2);
    lo0 += b2f(u0 & 0xffffu)*w0; hi0 += b2f(u0 >> 16)*w0;
  }
  unsigned* o = (unsigned*)(agg + ((size_t)b*NN + v)*DH);
  o[l] = pack2(lo0+lo1+lo2+lo3, hi0+hi1+hi2+hi3);
}

// ---------------- MFMA GEMM: (64 rows of one batch) x (K) @ Wt[128][K] ----------------
// EPI=0: write C bf16 (pre-norm) + fused GraphNorm stats atomics (red_out = ssum, ssq after)
// EPI=1: lrelu(C + bias), sum over valid rows -> atomicAdd red_out (= z)

template<int K, int EPI>
__global__ __launch_bounds__(256) void k_mm(const unsigned short* __restrict__ A,
        const unsigned short* __restrict__ Wt, unsigned short* __restrict__ Cb,
        const float* __restrict__ bias, float* __restrict__ red_out, int B){
  constexpr int K2 = K*2;            // bytes per row
  constexpr int CPR = K/8;           // 16B chunks per row
  __shared__ __align__(16) char smem[64*K2 + 128*K2];
  char* sA = smem;
  char* sW = smem + 64*K2;
  int t = threadIdx.x;
  int b = blockIdx.x >> 4;
  int tile = blockIdx.x & 15;
  int rows = NN - tile*64; if (rows > 64) rows = 64;
  size_t row0 = (size_t)b*NN + tile*64;
  size_t Mtot = (size_t)B*NN;

  for (int i = t; i < 64*CPR; i += 256){
    int r = i/CPR, cb = i%CPR;
    size_t gr = row0 + r; if (gr >= Mtot) gr = Mtot - 1;
    uint4 v = *(const uint4*)(A + gr*K + cb*8);
    *(uint4*)(sA + r*K2 + ((cb*16) ^ ((r & 7) << 4))) = v;
  }
  for (int i = t; i < 128*CPR; i += 256){
    int n = i/CPR, cb = i%CPR;
    uint4 v = *(const uint4*)(Wt + n*K + cb*8);
    *(uint4*)(sW + n*K2 + ((cb*16) ^ ((n & 7) << 4))) = v;
  }
  __syncthreads();

  int w = t >> 6, l = t & 63;
  int lr = l & 15, lk = l >> 4;
  f32x4 acc[8] = {};
  int arow = w*16 + lr;
  #pragma unroll
  for (int kk = 0; kk < K/32; ++kk){
    int kb = kk*64 + lk*16;
    short8 a = *(const short8*)(sA + arow*K2 + (kb ^ ((arow & 7) << 4)));
    #pragma unroll
    for (int f = 0; f < 8; ++f){
      int n = f*16 + lr;
      short8 bf = *(const short8*)(sW + n*K2 + (kb ^ ((n & 7) << 4)));
      acc[f] = __builtin_amdgcn_mfma_f32_16x16x32_bf16(a, bf, acc[f], 0, 0, 0);
    }
  }
  __syncthreads();   // done with sA/sW; reuse as reduction buffer

  float* red = (float*)smem;   // [4][128] sums, then [4][128] sq
  float cs[8], cq[8];
  int rbase = w*16 + lk*4;
  #pragma unroll
  for (int f = 0; f < 8; ++f){
    int col = f*16 + lr;
    float bv = (EPI == 1) ? bias[col] : 0.f;
    float s = 0.f, q = 0.f;
    #pragma unroll
    for (int r = 0; r < 4; ++r){
      int row = rbase + r;
      bool ok = row < rows;
      float v = acc[f][r];
      if (EPI == 0){
        if (ok) Cb[(row0 + row)*DH + col] = f2b(v);
        s += ok ? v : 0.f;
        q += ok ? v*v : 0.f;
      } else {
        float u = lrelu(v + bv);
        s += ok ? u : 0.f;
      }
    }
    s += __shfl_xor(s, 16); s += __shfl_xor(s, 32);
    cs[f] = s;
    if (EPI == 0){ q += __shfl_xor(q, 16); q += __shfl_xor(q, 32); cq[f] = q; }
  }
  if (l < 16){
    #pragma unroll
    for (int f = 0; f < 8; ++f){
      red[w*128 + f*16 + l] = cs[f];
      if (EPI == 0) red[512 + w*128 + f*16 + l] = cq[f];
    }
  }
  __syncthreads();
  if (t < 128){
    float s = red[t] + red[128+t] + red[256+t] + red[384+t];
    atomicAdd(&red_out[(size_t)b*DH + t], s);
    if (EPI == 0){
      float q = red[512+t] + red[640+t] + red[768+t] + red[896+t];
      atomicAdd(&red_out[(size_t)B*DH + (size_t)b*DH + t], q);
    }
  }
}

// ---------------- GraphNorm: finalize stats ----------------

__global__ void k_finstats(const float* __restrict__ ssum, const float* __restrict__ ssq,
                           const float* __restrict__ alpha, const float* __restrict__ gamma,
                           float* __restrict__ am, float* __restrict__ ivg, int BD){
  int i = blockIdx.x*blockDim.x + threadIdx.x;
  if (i < BD){
    int d = i & (DH-1);
    float m   = ssum[i] * (1.f/NN);
    float ex2 = ssq [i] * (1.f/NN);
    float a = alpha[d];
    float var = ex2 - (2.f*a - a*a)*m*m;
    am [i] = a*m;
    ivg[i] = gamma[d]*rsqrtf(var + FEPS);
  }
}

// ---------------- norm + lrelu + bf16 + fused weighted-mean readout ----------------
// block = 8 rows of one batch; grid = B*125

__global__ __launch_bounds__(256) void k_norm(const unsigned short* __restrict__ hpre,
                       const float* __restrict__ am, const float* __restrict__ ivg,
                       const float* __restrict__ beta, const float* __restrict__ gw,
                       const float* __restrict__ ar, unsigned short* __restrict__ hbf,
                       float* __restrict__ out, int off){
  __shared__ float red[8][128];
  int bid = blockIdx.x;
  int b = bid/125, v0 = (bid%125)*8;
  int t = threadIdx.x;
  int r = t >> 5, d0 = (t & 31)*4;
  int v = v0 + r;
  size_t base = ((size_t)b*NN + v)*DH + d0;
  uint2 u = *(const uint2*)(hpre + base);
  float x0 = b2f(u.x & 0xffffu), x1 = b2f(u.x >> 16);
  float x2 = b2f(u.y & 0xffffu), x3 = b2f(u.y >> 16);
  int c = b*DH + d0;
  float4 amv = *(const float4*)(am + c);
  float4 igv = *(const float4*)(ivg + c);
  float4 bt  = *(const float4*)(beta + d0);
  float n0 = lrelu((x0 - amv.x)*igv.x + bt.x);
  float n1 = lrelu((x1 - amv.y)*igv.y + bt.y);
  float n2 = lrelu((x2 - amv.z)*igv.z + bt.z);
  float n3 = lrelu((x3 - amv.w)*igv.w + bt.w);
  uint2 o; o.x = pack2(n0, n1); o.y = pack2(n2, n3);
  *(uint2*)(hbf + base) = o;
  float gwar = gw[b*NN + v]*ar[v];
  *(float4*)&red[r][d0] = make_float4(gwar*n0, gwar*n1, gwar*n2, gwar*n3);
  __syncthreads();
  if (t < 128){
    float s = 0.f;
    #pragma unroll
    for (int j = 0; j < 8; ++j) s += red[j][t];
    atomicAdd(&out[(size_t)b*640 + off + t], s*(1.f/NN));
  }
}

// ---------------- rho: z(128) @ rhoW(128x64) ----------------

__global__ void k_rho(const float* __restrict__ z, const float* __restrict__ Wm,
                      const float* __restrict__ bias, float* __restrict__ out, int off){
  int b = blockIdx.x;
  int d = threadIdx.x; // 64
  float acc = bias[d];
  const float* zb = z + b*DH;
  for (int k = 0; k < DH; ++k) acc += zb[k]*Wm[k*RD + d];
  out[(size_t)b*640 + off + d] = lrelu(acc);
}

// ---------------- weighted mean of raw x (piece 0) ----------------

__global__ void k_wmean0(const float* __restrict__ h, const float* __restrict__ gw,
                         const float* __restrict__ ar, float* __restrict__ out, int off){
  int b = blockIdx.x >> 3, ch = blockIdx.x & 7, t = threadIdx.x; // 64
  float acc = 0.f;
  const float* hb  = h  + ((size_t)b*NN + (size_t)ch*125)*FIN;
  const float* gwb = gw + (size_t)b*NN + (size_t)ch*125;
  const float* arb = ar + ch*125;
  for (int v = 0; v < 125; ++v) acc += gwb[v]*arb[v]*hb[(size_t)v*FIN + t];
  atomicAdd(&out[(size_t)b*640 + off + t], acc*(1.f/NN));
}

__global__ void k_flrelu(float* o, int n){
  int i = blockIdx.x*blockDim.x + threadIdx.x;
  if (i < n) o[i] = lrelu(o[i]);
}

// ---------------- launcher ----------------

extern "C" void kernel_launch(void* const* d_in, const int* in_sizes, int n_in,
                              void* d_out, int out_size, void* d_ws, size_t ws_size,
                              hipStream_t stream){
  const float* x    = (const float*)d_in[0];
  const float* ew   = (const float*)d_in[1];
  const float* gw   = (const float*)d_in[2];
  const float* W1   = (const float*)d_in[3];
  const float* W2   = (const float*)d_in[4];
  const float* W3   = (const float*)d_in[5];
  const float* sup  = (const float*)d_in[6];
  const float* AR   = (const float*)d_in[7];
  const float* gam  = (const float*)d_in[8];
  const float* bet  = (const float*)d_in[9];
  const float* alp  = (const float*)d_in[10];
  const float* phiW = (const float*)d_in[11];
  const float* phib = (const float*)d_in[12];
  const float* rhoW = (const float*)d_in[13];
  const float* rhob = (const float*)d_in[14];
  const int*   src  = (const int*)d_in[15];
  const int*   dst  = (const int*)d_in[16];
  float* out = (float*)d_out;

  int B = in_sizes[0] / (NN*FIN);
  size_t M = (size_t)B*NN;

  float* w = (float*)d_ws;
  size_t p = 0;
  int* deg_o = (int*)(w+p); p += 1024;
  int* deg_i = (int*)(w+p); p += 1024;
  int* fillc = (int*)(w+p); p += 1024;
  float* nout = w+p; p += 1024;
  float* nin  = w+p; p += 1024;
  int* rp     = (int*)(w+p); p += 1024;
  int* csr_s  = (int*)(w+p); p += 8192;
  int* csr_e  = (int*)(w+p); p += 8192;
  int* csr_d  = (int*)(w+p); p += 8192;
  float* ssum = w+p; p += (size_t)B*DH;   // ssq, zbuf must follow (fused memset)
  float* ssq  = w+p; p += (size_t)B*DH;
  float* zbuf = w+p; p += (size_t)B*DH;
  float* am   = w+p; p += (size_t)B*DH;
  float* ivg  = w+p; p += (size_t)B*DH;
  unsigned short* wt = (unsigned short*)(w+p); p += 45056;    // 90112 bf16
  float* wcomb = w+p; p += (size_t)3*B*NE;
  unsigned short* hpre = (unsigned short*)(w+p); p += M*DH/2; // bf16 pre-norm
  unsigned short* hbf  = (unsigned short*)(w+p); p += M*DH/2; // bf16 normalized
  unsigned short* agg  = (unsigned short*)(w+p); p += M*DH/2; // bf16 gathered

  hipMemsetAsync(deg_o, 0, 3*1024*sizeof(int), stream);
  hipMemsetAsync(out, 0, (size_t)out_size*sizeof(float), stream);

  k_count<<<(NE+255)/256, 256, 0, stream>>>(src, dst, deg_o, deg_i);
  k_prep <<<1, 1024, 0, stream>>>(deg_o, deg_i, nout, nin, rp);
  k_fill <<<(NE+255)/256, 256, 0, stream>>>(src, dst, rp, fillc, csr_s, csr_e, csr_d);
  k_wcomb<<<dim3((NE+255)/256, B, 3), 256, 0, stream>>>(ew, sup, nout, nin, csr_s, csr_e, csr_d, wcomb);
  k_prepw<<<352, 256, 0, stream>>>(W1, W2, W3, phiW, wt);

  k_wmean0<<<B*8, FIN, 0, stream>>>(x, gw, AR, out, 0);

  const int off_uro[3] = {64, 256, 448};
  const int off_wm [3] = {128, 320, 512};
  const int wt_off [3] = {0, 8192, 24576};

  for (int i = 0; i < 3; ++i){
    hipMemsetAsync(ssum, 0, 3*(size_t)B*DH*sizeof(float), stream);

    if (i == 0){
      k_gath0<<<B*250, 256, 0, stream>>>(x, wcomb, rp, csr_s, agg);
      k_mm<FIN,0><<<B*16, 256, 0, stream>>>(agg, wt, hpre, nullptr, ssum, B);
    } else {
      k_gathB<<<B*250, 256, 0, stream>>>(hbf, wcomb + (size_t)i*B*NE, rp, csr_s, agg);
      k_mm<DH,0><<<B*16, 256, 0, stream>>>(agg, wt + wt_off[i], hpre, nullptr, ssum, B);
    }

    k_finstats<<<(B*DH+255)/256, 256, 0, stream>>>(ssum, ssq, alp + i*DH, gam + i*DH, am, ivg, B*DH);
    k_norm<<<B*125, 256, 0, stream>>>(hpre, am, ivg, bet + i*DH, gw, AR + (size_t)(i+1)*NN, hbf, out, off_wm[i]);

    k_mm<DH,1><<<B*16, 256, 0, stream>>>(hbf, wt + 40960 + i*16384, nullptr, phib + i*DH, zbuf, B);
    k_rho<<<B, RD, 0, stream>>>(zbuf, rhoW + (size_t)i*DH*RD, rhob + i*RD, out, off_uro[i]);
  }

  k_flrelu<<<(B*640+255)/256, 256, 0, stream>>>(out, B*640);
}

// Round 4
// 353.596 us; speedup vs baseline: 2.9627x; 1.1991x over previous
//
#include <hip/hip_runtime.h>
#include <cstddef>

#define NN 1000
#define NE 8000
#define FIN 64
#define DH 128
#define RD 64
#define FEPS 1e-5f
#define WCCH 32   // ceil(NE/256)

typedef short short8 __attribute__((ext_vector_type(8)));
typedef float f32x4 __attribute__((ext_vector_type(4)));

__device__ __forceinline__ float lrelu(float x){ return x > 0.f ? x : 0.01f*x; }

__device__ __forceinline__ unsigned short f2b(float x){
  union { float f; unsigned int u; } v; v.f = x;
  unsigned int r = (v.u + 0x7fffu + ((v.u >> 16) & 1u)) >> 16;
  return (unsigned short)r;
}
__device__ __forceinline__ float b2f(unsigned int lo16){
  union { unsigned int u; float f; } v; v.u = lo16 << 16; return v.f;
}
__device__ __forceinline__ unsigned int pack2(float a, float b){
  return (unsigned int)f2b(a) | ((unsigned int)f2b(b) << 16);
}

// ---------------- topology: count + scan + CSR fill, one block ----------------

__global__ __launch_bounds__(1024) void k_topo(const int* __restrict__ src,
                       const int* __restrict__ dst,
                       float* nout, float* nin, int* rp,
                       int* csr_s, int* csr_e, int* csr_d){
  __shared__ int sdo[1024], sdi[1024], ssc[1024], sfill[1024];
  int t = threadIdx.x;
  sdo[t] = 0; sdi[t] = 0;
  __syncthreads();
  for (int e = t; e < NE; e += 1024){
    atomicAdd(&sdo[src[e]], 1);
    atomicAdd(&sdi[dst[e]], 1);
  }
  __syncthreads();
  int d = sdi[t];
  ssc[t] = d; __syncthreads();
  for (int off = 1; off < 1024; off <<= 1){
    int v = (t >= off) ? ssc[t-off] : 0;
    __syncthreads();
    ssc[t] += v;
    __syncthreads();
  }
  int myrp = ssc[t] - d;
  if (t < NN){
    rp[t] = myrp;
    nin[t]  = rsqrtf((float)max(sdi[t], 1));
    nout[t] = rsqrtf((float)max(sdo[t], 1));
  }
  if (t == NN-1) rp[NN] = ssc[t];
  sfill[t] = myrp;
  __syncthreads();
  for (int e = t; e < NE; e += 1024){
    int dn = dst[e];
    int pos = atomicAdd(&sfill[dn], 1);
    csr_s[pos] = src[e];
    csr_e[pos] = e;
    csr_d[pos] = dn;
  }
}

// ---------------- misc: wcomb + weight prep + wmean0, one kernel ----------------

__global__ __launch_bounds__(256) void k_misc(const float* __restrict__ ew,
        const float* __restrict__ sup, const float* __restrict__ nout,
        const float* __restrict__ nin, const int* __restrict__ csr_s,
        const int* __restrict__ csr_e, const int* __restrict__ csr_d,
        float* __restrict__ wc,
        const float* __restrict__ W1, const float* __restrict__ W2,
        const float* __restrict__ W3, const float* __restrict__ phiW,
        unsigned short* __restrict__ wt,
        const float* __restrict__ x, const float* __restrict__ gw,
        const float* __restrict__ AR, float* __restrict__ out, int B){
  __shared__ float red[4][64];
  int bid = blockIdx.x, t = threadIdx.x;
  int nwc = WCCH*B*3;
  if (bid < nwc){
    int layer = bid/(WCCH*B);
    int rem = bid - layer*WCCH*B;
    int b = rem/WCCH, c = rem - b*WCCH;
    int k = c*256 + t;
    if (k < NE){
      int e = csr_e[k], s = csr_s[k], dn = csr_d[k];
      wc[((size_t)layer*B + b)*NE + k] =
          ew[(size_t)b*NE + e]*sup[(size_t)layer*NE + e]*nout[s]*nin[dn];
    }
  } else if (bid < nwc + 352){
    int i = (bid - nwc)*256 + t;
    if (i < 8192){                      // W1: 64x128 -> [128][64]
      int n = i >> 6, k = i & 63;
      wt[i] = f2b(W1[k*128 + n]);
    } else if (i < 24576){              // W2: 128x128 -> [128][128]
      int j = i - 8192; int n = j >> 7, k = j & 127;
      wt[i] = f2b(W2[k*128 + n]);
    } else if (i < 40960){              // W3
      int j = i - 24576; int n = j >> 7, k = j & 127;
      wt[i] = f2b(W3[k*128 + n]);
    } else if (i < 90112){              // phiW[3]
      int j = i - 40960; int m = j >> 14; int jj = j & 16383;
      int n = jj >> 7, k = jj & 127;
      wt[i] = f2b(phiW[m*16384 + k*128 + n]);
    }
  } else {
    int wb = bid - nwc - 352;           // 0 .. 4B-1
    int b = wb >> 2, q = wb & 3;
    int r = t >> 6, l = t & 63;
    float acc = 0.f;
    int v0 = q*250;
    for (int v = v0 + r; v < v0 + 250; v += 4)
      acc += gw[(size_t)b*NN + v]*AR[v]*x[((size_t)b*NN + v)*FIN + l];
    red[r][l] = acc;
    __syncthreads();
    if (t < 64){
      float s = red[0][t]+red[1][t]+red[2][t]+red[3][t];
      atomicAdd(&out[(size_t)b*640 + t], s*(1.f/NN));
    }
  }
}

// ---------------- gather layer 0: x fp32 (FIN=64), 4 edges/wave ----------------

__global__ __launch_bounds__(256) void k_gath0(const float* __restrict__ x,
        const float* __restrict__ wc, const int* __restrict__ rp,
        const int* __restrict__ csr_s, unsigned short* __restrict__ agg,
        float* __restrict__ zero0, int nzero4){
  if (blockIdx.x < 48){
    int idx = blockIdx.x*256 + threadIdx.x;
    if (idx < nzero4) ((float4*)zero0)[idx] = make_float4(0.f,0.f,0.f,0.f);
  }
  int nwg8 = gridDim.x >> 3;
  int lid = (blockIdx.x & 7)*nwg8 + (blockIdx.x >> 3);
  int b = lid/250, v4 = lid%250;
  int wv = threadIdx.x >> 6, l = threadIdx.x & 63;
  int g = l >> 4, j = l & 15;
  int v = v4*4 + wv;
  int kb = rp[v], ke = rp[v+1];
  const float* xb  = x + (size_t)b*NN*FIN;
  const float* wcb = wc + (size_t)b*NE;
  float a0=0.f, a1=0.f, a2=0.f, a3=0.f;
  for (int k0 = kb; k0 < ke; k0 += 4){
    int k = k0 + g;
    bool ok = k < ke;
    int s = ok ? csr_s[k] : csr_s[kb];
    float wgt = ok ? wcb[k] : 0.f;
    float4 xr = *(const float4*)(xb + s*FIN + j*4);
    a0 = fmaf(xr.x, wgt, a0);
    a1 = fmaf(xr.y, wgt, a1);
    a2 = fmaf(xr.z, wgt, a2);
    a3 = fmaf(xr.w, wgt, a3);
  }
  a0 += __shfl_xor(a0,16); a0 += __shfl_xor(a0,32);
  a1 += __shfl_xor(a1,16); a1 += __shfl_xor(a1,32);
  a2 += __shfl_xor(a2,16); a2 += __shfl_xor(a2,32);
  a3 += __shfl_xor(a3,16); a3 += __shfl_xor(a3,32);
  if (g == 0){
    uint2 o; o.x = pack2(a0,a1); o.y = pack2(a2,a3);
    *(uint2*)(agg + ((size_t)b*NN + v)*FIN + j*4) = o;
  }
}

// ---------------- gather layers 1,2: hpre bf16 + on-the-fly norm ----------------

__global__ __launch_bounds__(256) void k_gathB(const unsigned short* __restrict__ h,
        const float* __restrict__ wc, const float* __restrict__ ivg,
        const float* __restrict__ pc, const int* __restrict__ rp,
        const int* __restrict__ csr_s, unsigned short* __restrict__ agg,
        float* __restrict__ zero0, int nzero4){
  if (blockIdx.x < 48){
    int idx = blockIdx.x*256 + threadIdx.x;
    if (idx < nzero4) ((float4*)zero0)[idx] = make_float4(0.f,0.f,0.f,0.f);
  }
  int nwg8 = gridDim.x >> 3;
  int lid = (blockIdx.x & 7)*nwg8 + (blockIdx.x >> 3);
  int b = lid/250, v4 = lid%250;
  int wv = threadIdx.x >> 6, l = threadIdx.x & 63;
  int g = l >> 4, j = l & 15;
  int v = v4*4 + wv;
  int kb = rp[v], ke = rp[v+1];
  const unsigned short* hb = h + (size_t)b*NN*DH;
  const float* wcb = wc + (size_t)b*NE;
  int cbase = b*DH + j*8;
  float ig[8], pp[8];
  *(float4*)&ig[0] = *(const float4*)(ivg + cbase);
  *(float4*)&ig[4] = *(const float4*)(ivg + cbase + 4);
  *(float4*)&pp[0] = *(const float4*)(pc + cbase);
  *(float4*)&pp[4] = *(const float4*)(pc + cbase + 4);
  float acc[8] = {0.f,0.f,0.f,0.f,0.f,0.f,0.f,0.f};
  for (int k0 = kb; k0 < ke; k0 += 4){
    int k = k0 + g;
    bool ok = k < ke;
    int s = ok ? csr_s[k] : csr_s[kb];
    float wgt = ok ? wcb[k] : 0.f;
    uint4 u = *(const uint4*)(hb + s*DH + j*8);
    float xv[8];
    xv[0] = b2f(u.x & 0xffffu); xv[1] = b2f(u.x >> 16);
    xv[2] = b2f(u.y & 0xffffu); xv[3] = b2f(u.y >> 16);
    xv[4] = b2f(u.z & 0xffffu); xv[5] = b2f(u.z >> 16);
    xv[6] = b2f(u.w & 0xffffu); xv[7] = b2f(u.w >> 16);
    #pragma unroll
    for (int d2 = 0; d2 < 8; ++d2){
      float nv = fmaf(xv[d2], ig[d2], pp[d2]);
      nv = fmaxf(nv, 0.01f*nv);          // lrelu
      acc[d2] = fmaf(nv, wgt, acc[d2]);
    }
  }
  #pragma unroll
  for (int d2 = 0; d2 < 8; ++d2){
    acc[d2] += __shfl_xor(acc[d2], 16);
    acc[d2] += __shfl_xor(acc[d2], 32);
  }
  if (g == 0){
    uint4 o;
    o.x = pack2(acc[0],acc[1]); o.y = pack2(acc[2],acc[3]);
    o.z = pack2(acc[4],acc[5]); o.w = pack2(acc[6],acc[7]);
    *(uint4*)(agg + ((size_t)b*NN + v)*DH + j*8) = o;
  }
}

// ---------------- conv MFMA GEMM + fused stats (ssum/ssq atomics) ----------------

template<int K>
__global__ __launch_bounds__(256) void k_conv(const unsigned short* __restrict__ A,
        const unsigned short* __restrict__ Wt, unsigned short* __restrict__ Cb,
        float* __restrict__ red_out, int B){
  constexpr int K2 = K*2;
  constexpr int CPR = K/8;
  __shared__ __align__(16) char smem[64*K2 + 128*K2];
  char* sA = smem;
  char* sW = smem + 64*K2;
  int t = threadIdx.x;
  int b = blockIdx.x >> 4;
  int tile = blockIdx.x & 15;
  int rows = NN - tile*64; if (rows > 64) rows = 64;
  size_t row0 = (size_t)b*NN + tile*64;
  size_t Mtot = (size_t)B*NN;

  for (int i = t; i < 64*CPR; i += 256){
    int r = i/CPR, cb = i%CPR;
    size_t gr = row0 + r; if (gr >= Mtot) gr = Mtot - 1;
    uint4 v = *(const uint4*)(A + gr*K + cb*8);
    *(uint4*)(sA + r*K2 + ((cb*16) ^ ((r & 7) << 4))) = v;
  }
  for (int i = t; i < 128*CPR; i += 256){
    int n = i/CPR, cb = i%CPR;
    uint4 v = *(const uint4*)(Wt + n*K + cb*8);
    *(uint4*)(sW + n*K2 + ((cb*16) ^ ((n & 7) << 4))) = v;
  }
  __syncthreads();

  int w = t >> 6, l = t & 63;
  int lr = l & 15, lk = l >> 4;
  f32x4 acc[8] = {};
  int arow = w*16 + lr;
  #pragma unroll
  for (int kk = 0; kk < K/32; ++kk){
    int kb = kk*64 + lk*16;
    short8 a = *(const short8*)(sA + arow*K2 + (kb ^ ((arow & 7) << 4)));
    #pragma unroll
    for (int f = 0; f < 8; ++f){
      int n = f*16 + lr;
      short8 bf = *(const short8*)(sW + n*K2 + (kb ^ ((n & 7) << 4)));
      acc[f] = __builtin_amdgcn_mfma_f32_16x16x32_bf16(a, bf, acc[f], 0, 0, 0);
    }
  }
  __syncthreads();

  float* red = (float*)smem;
  float cs[8], cq[8];
  int rbase = w*16 + lk*4;
  #pragma unroll
  for (int f = 0; f < 8; ++f){
    int col = f*16 + lr;
    float s = 0.f, q = 0.f;
    #pragma unroll
    for (int r = 0; r < 4; ++r){
      int row = rbase + r;
      bool ok = row < rows;
      float v = acc[f][r];
      if (ok) Cb[(row0 + row)*DH + col] = f2b(v);
      s += ok ? v : 0.f;
      q += ok ? v*v : 0.f;
    }
    s += __shfl_xor(s, 16); s += __shfl_xor(s, 32);
    q += __shfl_xor(q, 16); q += __shfl_xor(q, 32);
    cs[f] = s; cq[f] = q;
  }
  if (l < 16){
    #pragma unroll
    for (int f = 0; f < 8; ++f){
      red[w*128 + f*16 + l] = cs[f];
      red[512 + w*128 + f*16 + l] = cq[f];
    }
  }
  __syncthreads();
  if (t < 128){
    float s = red[t] + red[128+t] + red[256+t] + red[384+t];
    atomicAdd(&red_out[(size_t)b*DH + t], s);
    float q = red[512+t] + red[640+t] + red[768+t] + red[896+t];
    atomicAdd(&red_out[(size_t)B*DH + (size_t)b*DH + t], q);
  }
}

// ---------------- finalize stats: ivg = gamma*rsqrt(var), p = beta - a*m*ivg ----

__global__ void k_finstats(const float* __restrict__ ssum, const float* __restrict__ ssq,
                           const float* __restrict__ alpha, const float* __restrict__ gamma,
                           const float* __restrict__ beta,
                           float* __restrict__ ivg, float* __restrict__ pc, int BD){
  int i = blockIdx.x*blockDim.x + threadIdx.x;
  if (i < BD){
    int d = i & (DH-1);
    float m   = ssum[i] * (1.f/NN);
    float ex2 = ssq [i] * (1.f/NN);
    float a = alpha[d];
    float var = ex2 - (2.f*a - a*a)*m*m;
    float g = gamma[d]*rsqrtf(var + FEPS);
    ivg[i] = g;
    pc [i] = beta[d] - a*m*g;
  }
}

// ---------------- phi MFMA: norm-in-staging, z-reduce + fused wmean ----------------

__global__ __launch_bounds__(256) void k_phi(const unsigned short* __restrict__ hpre,
        const unsigned short* __restrict__ Wt, const float* __restrict__ ivg,
        const float* __restrict__ pc, const float* __restrict__ bias,
        const float* __restrict__ gw, const float* __restrict__ ar,
        float* __restrict__ zout, float* __restrict__ out, int off, int B){
  __shared__ __align__(16) char smem[64*256 + 128*256];
  __shared__ float sgw[64];
  char* sA = smem;
  char* sW = smem + 64*256;
  int t = threadIdx.x;
  int b = blockIdx.x >> 4;
  int tile = blockIdx.x & 15;
  int rows = NN - tile*64; if (rows > 64) rows = 64;
  size_t row0 = (size_t)b*NN + tile*64;

  // stage A with norm + lrelu, pack bf16
  for (int i = t; i < 64*16; i += 256){
    int r = i >> 4, cb = i & 15;
    int rr = (r < rows) ? r : 0;
    uint4 u = *(const uint4*)(hpre + (row0 + rr)*DH + cb*8);
    int c0 = b*DH + cb*8;
    float4 g1 = *(const float4*)(ivg + c0), g2 = *(const float4*)(ivg + c0 + 4);
    float4 p1 = *(const float4*)(pc + c0),  p2 = *(const float4*)(pc + c0 + 4);
    float xv[8];
    xv[0] = b2f(u.x & 0xffffu); xv[1] = b2f(u.x >> 16);
    xv[2] = b2f(u.y & 0xffffu); xv[3] = b2f(u.y >> 16);
    xv[4] = b2f(u.z & 0xffffu); xv[5] = b2f(u.z >> 16);
    xv[6] = b2f(u.w & 0xffffu); xv[7] = b2f(u.w >> 16);
    float gg[8] = {g1.x,g1.y,g1.z,g1.w,g2.x,g2.y,g2.z,g2.w};
    float pv[8] = {p1.x,p1.y,p1.z,p1.w,p2.x,p2.y,p2.z,p2.w};
    float nv[8];
    #pragma unroll
    for (int d2 = 0; d2 < 8; ++d2){
      float n0 = fmaf(xv[d2], gg[d2], pv[d2]);
      nv[d2] = fmaxf(n0, 0.01f*n0);
    }
    uint4 o;
    o.x = pack2(nv[0],nv[1]); o.y = pack2(nv[2],nv[3]);
    o.z = pack2(nv[4],nv[5]); o.w = pack2(nv[6],nv[7]);
    *(uint4*)(sA + r*256 + ((cb*16) ^ ((r & 7) << 4))) = o;
  }
  for (int i = t; i < 128*16; i += 256){
    int n = i >> 4, cb = i & 15;
    uint4 v = *(const uint4*)(Wt + n*DH + cb*8);
    *(uint4*)(sW + n*256 + ((cb*16) ^ ((n & 7) << 4))) = v;
  }
  if (t < 64){
    int vr = tile*64 + t;
    sgw[t] = (vr < NN) ? gw[(size_t)b*NN + vr]*ar[vr] : 0.f;
  }
  __syncthreads();

  int w = t >> 6, l = t & 63;
  int lr = l & 15, lk = l >> 4;
  f32x4 acc[8] = {};
  int arow = w*16 + lr;
  #pragma unroll
  for (int kk = 0; kk < 4; ++kk){
    int kb = kk*64 + lk*16;
    short8 a = *(const short8*)(sA + arow*256 + (kb ^ ((arow & 7) << 4)));
    #pragma unroll
    for (int f = 0; f < 8; ++f){
      int n = f*16 + lr;
      short8 bf = *(const short8*)(sW + n*256 + (kb ^ ((n & 7) << 4)));
      acc[f] = __builtin_amdgcn_mfma_f32_16x16x32_bf16(a, bf, acc[f], 0, 0, 0);
    }
  }
  __syncthreads();   // all sW reads done; reuse sW area for reduction

  float* red = (float*)sW;
  float cs[8];
  int rbase = w*16 + lk*4;
  #pragma unroll
  for (int f = 0; f < 8; ++f){
    int col = f*16 + lr;
    float bv = bias[col];
    float s = 0.f;
    #pragma unroll
    for (int r = 0; r < 4; ++r){
      int row = rbase + r;
      float u = lrelu(acc[f][r] + bv);
      s += (row < rows) ? u : 0.f;
    }
    s += __shfl_xor(s, 16); s += __shfl_xor(s, 32);
    cs[f] = s;
  }
  if (l < 16){
    #pragma unroll
    for (int f = 0; f < 8; ++f) red[w*128 + f*16 + l] = cs[f];
  }
  __syncthreads();
  if (t < 128){
    float s = red[t] + red[128+t] + red[256+t] + red[384+t];
    atomicAdd(&zout[(size_t)b*DH + t], s);
  } else {
    int col = t - 128;
    float s = 0.f;
    for (int r = 0; r < 64; ++r){
      int byteoff = r*256 + (((col >> 3)*16) ^ ((r & 7) << 4)) + (col & 7)*2;
      s += sgw[r]*b2f(*(const unsigned short*)(sA + byteoff));
    }
    atomicAdd(&out[(size_t)b*640 + off + col], s*(1.f/NN));
  }
}

// ---------------- rho (all 3 layers in one dispatch) ----------------

__global__ void k_rho(const float* __restrict__ statz, const float* __restrict__ rhoW,
                      const float* __restrict__ rhob, float* __restrict__ out, int B){
  int i = blockIdx.x / B, b = blockIdx.x % B;
  int d = threadIdx.x; // 64
  const float* z = statz + (size_t)i*3*B*DH + (size_t)2*B*DH + (size_t)b*DH;
  float acc = rhob[i*RD + d];
  const float* Wm = rhoW + (size_t)i*DH*RD;
  for (int k = 0; k < DH; ++k) acc = fmaf(z[k], Wm[k*RD + d], acc);
  out[(size_t)b*640 + 64 + i*192 + d] = lrelu(acc);
}

__global__ void k_flrelu(float* o, int n){
  int i = blockIdx.x*blockDim.x + threadIdx.x;
  if (i < n) o[i] = lrelu(o[i]);
}

// ---------------- launcher ----------------

extern "C" void kernel_launch(void* const* d_in, const int* in_sizes, int n_in,
                              void* d_out, int out_size, void* d_ws, size_t ws_size,
                              hipStream_t stream){
  const float* x    = (const float*)d_in[0];
  const float* ew   = (const float*)d_in[1];
  const float* gw   = (const float*)d_in[2];
  const float* W1   = (const float*)d_in[3];
  const float* W2   = (const float*)d_in[4];
  const float* W3   = (const float*)d_in[5];
  const float* sup  = (const float*)d_in[6];
  const float* AR   = (const float*)d_in[7];
  const float* gam  = (const float*)d_in[8];
  const float* bet  = (const float*)d_in[9];
  const float* alp  = (const float*)d_in[10];
  const float* phiW = (const float*)d_in[11];
  const float* phib = (const float*)d_in[12];
  const float* rhoW = (const float*)d_in[13];
  const float* rhob = (const float*)d_in[14];
  const int*   src  = (const int*)d_in[15];
  const int*   dst  = (const int*)d_in[16];
  float* out = (float*)d_out;

  int B = in_sizes[0] / (NN*FIN);
  size_t M = (size_t)B*NN;
  size_t BD = (size_t)B*DH;

  float* w = (float*)d_ws;
  size_t p = 0;
  float* nout = w+p; p += 1024;
  float* nin  = w+p; p += 1024;
  int* rp     = (int*)(w+p); p += 1024;
  int* csr_s  = (int*)(w+p); p += 8192;
  int* csr_e  = (int*)(w+p); p += 8192;
  int* csr_d  = (int*)(w+p); p += 8192;
  float* statz = w+p; p += 3*3*BD;           // per layer: [ssum | ssq | zbuf]
  float* ivgP = w+p; p += 3*BD;
  float* pP   = w+p; p += 3*BD;
  unsigned short* wt = (unsigned short*)(w+p); p += 45056;   // 90112 bf16
  float* wcomb = w+p; p += (size_t)3*B*NE;
  unsigned short* hpre = (unsigned short*)(w+p); p += M*DH/2;
  unsigned short* agg  = (unsigned short*)(w+p); p += M*DH/2;

  hipMemsetAsync(out, 0, (size_t)out_size*sizeof(float), stream);

  k_topo<<<1, 1024, 0, stream>>>(src, dst, nout, nin, rp, csr_s, csr_e, csr_d);
  k_misc<<<WCCH*B*3 + 352 + B*4, 256, 0, stream>>>(
      ew, sup, nout, nin, csr_s, csr_e, csr_d, wcomb,
      W1, W2, W3, phiW, wt, x, gw, AR, out, B);

  const int wt_off[3] = {0, 8192, 24576};
  int nzero4 = (int)(3*BD/4);

  for (int i = 0; i < 3; ++i){
    float* SS = statz + (size_t)i*3*BD;
    if (i == 0){
      k_gath0<<<B*250, 256, 0, stream>>>(x, wcomb, rp, csr_s, agg, SS, nzero4);
      k_conv<FIN><<<B*16, 256, 0, stream>>>(agg, wt, hpre, SS, B);
    } else {
      k_gathB<<<B*250, 256, 0, stream>>>(hpre, wcomb + (size_t)i*B*NE,
          ivgP + (size_t)(i-1)*BD, pP + (size_t)(i-1)*BD, rp, csr_s, agg, SS, nzero4);
      k_conv<DH><<<B*16, 256, 0, stream>>>(agg, wt + wt_off[i], hpre, SS, B);
    }
    k_finstats<<<(int)((BD+255)/256), 256, 0, stream>>>(SS, SS + BD,
        alp + i*DH, gam + i*DH, bet + i*DH, ivgP + (size_t)i*BD, pP + (size_t)i*BD, (int)BD);
    k_phi<<<B*16, 256, 0, stream>>>(hpre, wt + 40960 + i*16384,
        ivgP + (size_t)i*BD, pP + (size_t)i*BD, phib + i*DH, gw, AR + (size_t)(i+1)*NN,
        SS + 2*BD, out, 128 + i*192, B);
  }

  k_rho<<<3*B, RD, 0, stream>>>(statz, rhoW, rhob, out, B);
  k_flrelu<<<(B*640+255)/256, 256, 0, stream>>>(out, B*640);
}

// Round 5
// 339.935 us; speedup vs baseline: 3.0817x; 1.0402x over previous
//
#include <hip/hip_runtime.h>
#include <cstddef>

#define NN 1000
#define NE 8000
#define FIN 64
#define DH 128
#define RD 64
#define FEPS 1e-5f

typedef short short8 __attribute__((ext_vector_type(8)));
typedef float f32x4 __attribute__((ext_vector_type(4)));

__device__ __forceinline__ float lrelu(float x){ return x > 0.f ? x : 0.01f*x; }

__device__ __forceinline__ unsigned short f2b(float x){
  union { float f; unsigned int u; } v; v.f = x;
  unsigned int r = (v.u + 0x7fffu + ((v.u >> 16) & 1u)) >> 16;
  return (unsigned short)r;
}
__device__ __forceinline__ float b2f(unsigned int lo16){
  union { unsigned int u; float f; } v; v.u = lo16 << 16; return v.f;
}
__device__ __forceinline__ unsigned int pack2(float a, float b){
  return (unsigned int)f2b(a) | ((unsigned int)f2b(b) << 16);
}

// ---------------- topology: count + scan + CSR fill, one block ----------------

__global__ __launch_bounds__(1024) void k_topo(const int* __restrict__ src,
                       const int* __restrict__ dst,
                       float* nout, float* nin, int* rp,
                       int* csr_s, int* csr_e, int* csr_d){
  __shared__ int sdo[1024], sdi[1024], ssc[1024], sfill[1024];
  int t = threadIdx.x;
  sdo[t] = 0; sdi[t] = 0;
  __syncthreads();
  for (int e = t; e < NE; e += 1024){
    atomicAdd(&sdo[src[e]], 1);
    atomicAdd(&sdi[dst[e]], 1);
  }
  __syncthreads();
  int d = sdi[t];
  ssc[t] = d; __syncthreads();
  for (int off = 1; off < 1024; off <<= 1){
    int v = (t >= off) ? ssc[t-off] : 0;
    __syncthreads();
    ssc[t] += v;
    __syncthreads();
  }
  int myrp = ssc[t] - d;
  if (t < NN){
    rp[t] = myrp;
    nin[t]  = rsqrtf((float)max(sdi[t], 1));
    nout[t] = rsqrtf((float)max(sdo[t], 1));
  }
  if (t == NN-1) rp[NN] = ssc[t];
  sfill[t] = myrp;
  __syncthreads();
  for (int e = t; e < NE; e += 1024){
    int dn = dst[e];
    int pos = atomicAdd(&sfill[dn], 1);
    csr_s[pos] = src[e];
    csr_e[pos] = e;
    csr_d[pos] = dn;
  }
}

// ---------------- edge streams: ec[b][k] = {src, ew*nout*nin}; supn[l][k] ------

__global__ __launch_bounds__(256) void k_edge(const float* __restrict__ ew,
        const float* __restrict__ sup, const float* __restrict__ nout,
        const float* __restrict__ nin, const int* __restrict__ csr_s,
        const int* __restrict__ csr_e, const int* __restrict__ csr_d,
        int2* __restrict__ ec, float* __restrict__ supn, int B){
  int bid = blockIdx.x, t = threadIdx.x;
  if (bid < 4*B){
    int b = bid >> 2, q = bid & 3;
    const float* ewb = ew + (size_t)b*NE;
    int2* ecb = ec + (size_t)b*NE;
    for (int k = q*2000 + t; k < q*2000 + 2000; k += 256){
      int s = csr_s[k];
      float wv = ewb[csr_e[k]]*nout[s]*nin[csr_d[k]];
      int2 v; v.x = s; v.y = __float_as_int(wv);
      ecb[k] = v;
    }
  } else {
    int k = (bid - 4*B)*256 + t;
    if (k < 3*NE){
      int layer = k / NE, kk = k - layer*NE;
      supn[k] = sup[(size_t)layer*NE + csr_e[kk]];
    }
  }
}

// ---------------- misc: weight prep + wmean0 ----------------

__global__ __launch_bounds__(256) void k_misc(
        const float* __restrict__ W1, const float* __restrict__ W2,
        const float* __restrict__ W3, const float* __restrict__ phiW,
        unsigned short* __restrict__ wt,
        const float* __restrict__ x, const float* __restrict__ gw,
        const float* __restrict__ AR, float* __restrict__ out, int B){
  __shared__ float red[4][64];
  int bid = blockIdx.x, t = threadIdx.x;
  if (bid < 352){
    int i = bid*256 + t;
    if (i < 8192){                      // W1: 64x128 -> [128][64]
      int n = i >> 6, k = i & 63;
      wt[i] = f2b(W1[k*128 + n]);
    } else if (i < 24576){              // W2: 128x128 -> [128][128]
      int j = i - 8192; int n = j >> 7, k = j & 127;
      wt[i] = f2b(W2[k*128 + n]);
    } else if (i < 40960){              // W3
      int j = i - 24576; int n = j >> 7, k = j & 127;
      wt[i] = f2b(W3[k*128 + n]);
    } else if (i < 90112){              // phiW[3]
      int j = i - 40960; int m = j >> 14; int jj = j & 16383;
      int n = jj >> 7, k = jj & 127;
      wt[i] = f2b(phiW[m*16384 + k*128 + n]);
    }
  } else {
    int wb = bid - 352;                 // 0 .. 4B-1
    int b = wb >> 2, q = wb & 3;
    int r = t >> 6, l = t & 63;
    float acc = 0.f;
    int v0 = q*250;
    for (int v = v0 + r; v < v0 + 250; v += 4)
      acc += gw[(size_t)b*NN + v]*AR[v]*x[((size_t)b*NN + v)*FIN + l];
    red[r][l] = acc;
    __syncthreads();
    if (t < 64){
      float s = red[0][t]+red[1][t]+red[2][t]+red[3][t];
      atomicAdd(&out[(size_t)b*640 + t], s*(1.f/NN));
    }
  }
}

// ---------------- gather layer 0: x fp32 (FIN=64), 4 edges/wave ----------------

__global__ __launch_bounds__(256) void k_gath0(const float* __restrict__ x,
        const int2* __restrict__ ec, const float* __restrict__ sp,
        const int* __restrict__ rp, unsigned short* __restrict__ agg,
        float* __restrict__ zero0, int nzero4){
  if (blockIdx.x < 48){
    int idx = blockIdx.x*256 + threadIdx.x;
    if (idx < nzero4) ((float4*)zero0)[idx] = make_float4(0.f,0.f,0.f,0.f);
  }
  int nwg8 = gridDim.x >> 3;
  int lid = (blockIdx.x & 7)*nwg8 + (blockIdx.x >> 3);
  int b = lid/250, v4 = lid%250;
  int wv = threadIdx.x >> 6, l = threadIdx.x & 63;
  int g = l >> 4, j = l & 15;
  int v = v4*4 + wv;
  int kb = rp[v], ke = rp[v+1];
  const float* xb = x + (size_t)b*NN*FIN;
  const int2* ecb = ec + (size_t)b*NE;
  float a0=0.f, a1=0.f, a2=0.f, a3=0.f;
  for (int k0 = kb; k0 < ke; k0 += 4){
    int k = k0 + g;
    bool ok = k < ke;
    int kc = ok ? k : kb;
    int2 epk = ecb[kc];
    float wgt = ok ? __int_as_float(epk.y)*sp[kc] : 0.f;
    float4 xr = *(const float4*)(xb + epk.x*FIN + j*4);
    a0 = fmaf(xr.x, wgt, a0);
    a1 = fmaf(xr.y, wgt, a1);
    a2 = fmaf(xr.z, wgt, a2);
    a3 = fmaf(xr.w, wgt, a3);
  }
  a0 += __shfl_xor(a0,16); a0 += __shfl_xor(a0,32);
  a1 += __shfl_xor(a1,16); a1 += __shfl_xor(a1,32);
  a2 += __shfl_xor(a2,16); a2 += __shfl_xor(a2,32);
  a3 += __shfl_xor(a3,16); a3 += __shfl_xor(a3,32);
  if (g == 0){
    uint2 o; o.x = pack2(a0,a1); o.y = pack2(a2,a3);
    *(uint2*)(agg + ((size_t)b*NN + v)*FIN + j*4) = o;
  }
}

// ---------------- gather layers 1,2: hpre bf16 + on-the-fly norm ----------------

__global__ __launch_bounds__(256) void k_gathB(const unsigned short* __restrict__ h,
        const int2* __restrict__ ec, const float* __restrict__ sp,
        const float* __restrict__ ivg, const float* __restrict__ pc,
        const int* __restrict__ rp, unsigned short* __restrict__ agg,
        float* __restrict__ zero0, int nzero4){
  if (blockIdx.x < 48){
    int idx = blockIdx.x*256 + threadIdx.x;
    if (idx < nzero4) ((float4*)zero0)[idx] = make_float4(0.f,0.f,0.f,0.f);
  }
  int nwg8 = gridDim.x >> 3;
  int lid = (blockIdx.x & 7)*nwg8 + (blockIdx.x >> 3);
  int b = lid/250, v4 = lid%250;
  int wv = threadIdx.x >> 6, l = threadIdx.x & 63;
  int g = l >> 4, j = l & 15;
  int v = v4*4 + wv;
  int kb = rp[v], ke = rp[v+1];
  const unsigned short* hb = h + (size_t)b*NN*DH;
  const int2* ecb = ec + (size_t)b*NE;
  int cbase = b*DH + j*8;
  float ig[8], pp[8];
  *(float4*)&ig[0] = *(const float4*)(ivg + cbase);
  *(float4*)&ig[4] = *(const float4*)(ivg + cbase + 4);
  *(float4*)&pp[0] = *(const float4*)(pc + cbase);
  *(float4*)&pp[4] = *(const float4*)(pc + cbase + 4);
  float acc[8] = {0.f,0.f,0.f,0.f,0.f,0.f,0.f,0.f};
  for (int k0 = kb; k0 < ke; k0 += 4){
    int k = k0 + g;
    bool ok = k < ke;
    int kc = ok ? k : kb;
    int2 epk = ecb[kc];
    float wgt = ok ? __int_as_float(epk.y)*sp[kc] : 0.f;
    uint4 u = *(const uint4*)(hb + epk.x*DH + j*8);
    float xv[8];
    xv[0] = b2f(u.x & 0xffffu); xv[1] = b2f(u.x >> 16);
    xv[2] = b2f(u.y & 0xffffu); xv[3] = b2f(u.y >> 16);
    xv[4] = b2f(u.z & 0xffffu); xv[5] = b2f(u.z >> 16);
    xv[6] = b2f(u.w & 0xffffu); xv[7] = b2f(u.w >> 16);
    #pragma unroll
    for (int d2 = 0; d2 < 8; ++d2){
      float nv = fmaf(xv[d2], ig[d2], pp[d2]);
      nv = fmaxf(nv, 0.01f*nv);          // lrelu
      acc[d2] = fmaf(nv, wgt, acc[d2]);
    }
  }
  #pragma unroll
  for (int d2 = 0; d2 < 8; ++d2){
    acc[d2] += __shfl_xor(acc[d2], 16);
    acc[d2] += __shfl_xor(acc[d2], 32);
  }
  if (g == 0){
    uint4 o;
    o.x = pack2(acc[0],acc[1]); o.y = pack2(acc[2],acc[3]);
    o.z = pack2(acc[4],acc[5]); o.w = pack2(acc[6],acc[7]);
    *(uint4*)(agg + ((size_t)b*NN + v)*DH + j*8) = o;
  }
}

// ---------------- conv MFMA GEMM + fused stats (ssum/ssq atomics) ----------------

template<int K>
__global__ __launch_bounds__(256) void k_conv(const unsigned short* __restrict__ A,
        const unsigned short* __restrict__ Wt, unsigned short* __restrict__ Cb,
        float* __restrict__ red_out, int B){
  constexpr int K2 = K*2;
  constexpr int CPR = K/8;
  __shared__ __align__(16) char smem[64*K2 + 128*K2];
  char* sA = smem;
  char* sW = smem + 64*K2;
  int t = threadIdx.x;
  int b = blockIdx.x >> 4;
  int tile = blockIdx.x & 15;
  int rows = NN - tile*64; if (rows > 64) rows = 64;
  size_t row0 = (size_t)b*NN + tile*64;
  size_t Mtot = (size_t)B*NN;

  for (int i = t; i < 64*CPR; i += 256){
    int r = i/CPR, cb = i%CPR;
    size_t gr = row0 + r; if (gr >= Mtot) gr = Mtot - 1;
    uint4 v = *(const uint4*)(A + gr*K + cb*8);
    *(uint4*)(sA + r*K2 + ((cb*16) ^ ((r & 7) << 4))) = v;
  }
  for (int i = t; i < 128*CPR; i += 256){
    int n = i/CPR, cb = i%CPR;
    uint4 v = *(const uint4*)(Wt + n*K + cb*8);
    *(uint4*)(sW + n*K2 + ((cb*16) ^ ((n & 7) << 4))) = v;
  }
  __syncthreads();

  int w = t >> 6, l = t & 63;
  int lr = l & 15, lk = l >> 4;
  f32x4 acc[8] = {};
  int arow = w*16 + lr;
  #pragma unroll
  for (int kk = 0; kk < K/32; ++kk){
    int kb = kk*64 + lk*16;
    short8 a = *(const short8*)(sA + arow*K2 + (kb ^ ((arow & 7) << 4)));
    #pragma unroll
    for (int f = 0; f < 8; ++f){
      int n = f*16 + lr;
      short8 bf = *(const short8*)(sW + n*K2 + (kb ^ ((n & 7) << 4)));
      acc[f] = __builtin_amdgcn_mfma_f32_16x16x32_bf16(a, bf, acc[f], 0, 0, 0);
    }
  }
  __syncthreads();

  float* red = (float*)smem;
  float cs[8], cq[8];
  int rbase = w*16 + lk*4;
  #pragma unroll
  for (int f = 0; f < 8; ++f){
    int col = f*16 + lr;
    float s = 0.f, q = 0.f;
    #pragma unroll
    for (int r = 0; r < 4; ++r){
      int row = rbase + r;
      bool ok = row < rows;
      float v = acc[f][r];
      if (ok) Cb[(row0 + row)*DH + col] = f2b(v);
      s += ok ? v : 0.f;
      q += ok ? v*v : 0.f;
    }
    s += __shfl_xor(s, 16); s += __shfl_xor(s, 32);
    q += __shfl_xor(q, 16); q += __shfl_xor(q, 32);
    cs[f] = s; cq[f] = q;
  }
  if (l < 16){
    #pragma unroll
    for (int f = 0; f < 8; ++f){
      red[w*128 + f*16 + l] = cs[f];
      red[512 + w*128 + f*16 + l] = cq[f];
    }
  }
  __syncthreads();
  if (t < 128){
    float s = red[t] + red[128+t] + red[256+t] + red[384+t];
    atomicAdd(&red_out[(size_t)b*DH + t], s);
    float q = red[512+t] + red[640+t] + red[768+t] + red[896+t];
    atomicAdd(&red_out[(size_t)B*DH + (size_t)b*DH + t], q);
  }
}

// ---------------- finalize stats: ivg = gamma*rsqrt(var), p = beta - a*m*ivg ----

__global__ void k_finstats(const float* __restrict__ ssum, const float* __restrict__ ssq,
                           const float* __restrict__ alpha, const float* __restrict__ gamma,
                           const float* __restrict__ beta,
                           float* __restrict__ ivg, float* __restrict__ pc, int BD){
  int i = blockIdx.x*blockDim.x + threadIdx.x;
  if (i < BD){
    int d = i & (DH-1);
    float m   = ssum[i] * (1.f/NN);
    float ex2 = ssq [i] * (1.f/NN);
    float a = alpha[d];
    float var = ex2 - (2.f*a - a*a)*m*m;
    float g = gamma[d]*rsqrtf(var + FEPS);
    ivg[i] = g;
    pc [i] = beta[d] - a*m*g;
  }
}

// ---------------- phi MFMA: norm-in-staging, z-reduce + fused wmean ----------------

__global__ __launch_bounds__(256) void k_phi(const unsigned short* __restrict__ hpre,
        const unsigned short* __restrict__ Wt, const float* __restrict__ ivg,
        const float* __restrict__ pc, const float* __restrict__ bias,
        const float* __restrict__ gw, const float* __restrict__ ar,
        float* __restrict__ zout, float* __restrict__ out, int off, int B){
  __shared__ __align__(16) char smem[64*256 + 128*256];
  __shared__ float sgw[64];
  char* sA = smem;
  char* sW = smem + 64*256;
  int t = threadIdx.x;
  int b = blockIdx.x >> 4;
  int tile = blockIdx.x & 15;
  int rows = NN - tile*64; if (rows > 64) rows = 64;
  size_t row0 = (size_t)b*NN + tile*64;

  // stage A with norm + lrelu, pack bf16
  for (int i = t; i < 64*16; i += 256){
    int r = i >> 4, cb = i & 15;
    int rr = (r < rows) ? r : 0;
    uint4 u = *(const uint4*)(hpre + (row0 + rr)*DH + cb*8);
    int c0 = b*DH + cb*8;
    float4 g1 = *(const float4*)(ivg + c0), g2 = *(const float4*)(ivg + c0 + 4);
    float4 p1 = *(const float4*)(pc + c0),  p2 = *(const float4*)(pc + c0 + 4);
    float xv[8];
    xv[0] = b2f(u.x & 0xffffu); xv[1] = b2f(u.x >> 16);
    xv[2] = b2f(u.y & 0xffffu); xv[3] = b2f(u.y >> 16);
    xv[4] = b2f(u.z & 0xffffu); xv[5] = b2f(u.z >> 16);
    xv[6] = b2f(u.w & 0xffffu); xv[7] = b2f(u.w >> 16);
    float gg[8] = {g1.x,g1.y,g1.z,g1.w,g2.x,g2.y,g2.z,g2.w};
    float pv[8] = {p1.x,p1.y,p1.z,p1.w,p2.x,p2.y,p2.z,p2.w};
    float nv[8];
    #pragma unroll
    for (int d2 = 0; d2 < 8; ++d2){
      float n0 = fmaf(xv[d2], gg[d2], pv[d2]);
      nv[d2] = fmaxf(n0, 0.01f*n0);
    }
    uint4 o;
    o.x = pack2(nv[0],nv[1]); o.y = pack2(nv[2],nv[3]);
    o.z = pack2(nv[4],nv[5]); o.w = pack2(nv[6],nv[7]);
    *(uint4*)(sA + r*256 + ((cb*16) ^ ((r & 7) << 4))) = o;
  }
  for (int i = t; i < 128*16; i += 256){
    int n = i >> 4, cb = i & 15;
    uint4 v = *(const uint4*)(Wt + n*DH + cb*8);
    *(uint4*)(sW + n*256 + ((cb*16) ^ ((n & 7) << 4))) = v;
  }
  if (t < 64){
    int vr = tile*64 + t;
    sgw[t] = (vr < NN) ? gw[(size_t)b*NN + vr]*ar[vr] : 0.f;
  }
  __syncthreads();

  int w = t >> 6, l = t & 63;
  int lr = l & 15, lk = l >> 4;
  f32x4 acc[8] = {};
  int arow = w*16 + lr;
  #pragma unroll
  for (int kk = 0; kk < 4; ++kk){
    int kb = kk*64 + lk*16;
    short8 a = *(const short8*)(sA + arow*256 + (kb ^ ((arow & 7) << 4)));
    #pragma unroll
    for (int f = 0; f < 8; ++f){
      int n = f*16 + lr;
      short8 bf = *(const short8*)(sW + n*256 + (kb ^ ((n & 7) << 4)));
      acc[f] = __builtin_amdgcn_mfma_f32_16x16x32_bf16(a, bf, acc[f], 0, 0, 0);
    }
  }
  __syncthreads();   // all sW reads done; reuse sW area for reduction

  float* red = (float*)sW;
  float cs[8];
  int rbase = w*16 + lk*4;
  #pragma unroll
  for (int f = 0; f < 8; ++f){
    int col = f*16 + lr;
    float bv = bias[col];
    float s = 0.f;
    #pragma unroll
    for (int r = 0; r < 4; ++r){
      int row = rbase + r;
      float u = lrelu(acc[f][r] + bv);
      s += (row < rows) ? u : 0.f;
    }
    s += __shfl_xor(s, 16); s += __shfl_xor(s, 32);
    cs[f] = s;
  }
  if (l < 16){
    #pragma unroll
    for (int f = 0; f < 8; ++f) red[w*128 + f*16 + l] = cs[f];
  }
  __syncthreads();
  if (t < 128){
    float s = red[t] + red[128+t] + red[256+t] + red[384+t];
    atomicAdd(&zout[(size_t)b*DH + t], s);
  } else {
    int col = t - 128;
    float s = 0.f;
    for (int r = 0; r < 64; ++r){
      int byteoff = r*256 + (((col >> 3)*16) ^ ((r & 7) << 4)) + (col & 7)*2;
      s += sgw[r]*b2f(*(const unsigned short*)(sA + byteoff));
    }
    atomicAdd(&out[(size_t)b*640 + off + col], s*(1.f/NN));
  }
}

// ---------------- rho (all 3 layers in one dispatch) ----------------

__global__ void k_rho(const float* __restrict__ statz, const float* __restrict__ rhoW,
                      const float* __restrict__ rhob, float* __restrict__ out, int B){
  int i = blockIdx.x / B, b = blockIdx.x % B;
  int d = threadIdx.x; // 64
  const float* z = statz + (size_t)i*3*B*DH + (size_t)2*B*DH + (size_t)b*DH;
  float acc = rhob[i*RD + d];
  const float* Wm = rhoW + (size_t)i*DH*RD;
  for (int k = 0; k < DH; ++k) acc = fmaf(z[k], Wm[k*RD + d], acc);
  out[(size_t)b*640 + 64 + i*192 + d] = lrelu(acc);
}

__global__ void k_flrelu(float* o, int n){
  int i = blockIdx.x*blockDim.x + threadIdx.x;
  if (i < n) o[i] = lrelu(o[i]);
}

// ---------------- launcher ----------------

extern "C" void kernel_launch(void* const* d_in, const int* in_sizes, int n_in,
                              void* d_out, int out_size, void* d_ws, size_t ws_size,
                              hipStream_t stream){
  const float* x    = (const float*)d_in[0];
  const float* ew   = (const float*)d_in[1];
  const float* gw   = (const float*)d_in[2];
  const float* W1   = (const float*)d_in[3];
  const float* W2   = (const float*)d_in[4];
  const float* W3   = (const float*)d_in[5];
  const float* sup  = (const float*)d_in[6];
  const float* AR   = (const float*)d_in[7];
  const float* gam  = (const float*)d_in[8];
  const float* bet  = (const float*)d_in[9];
  const float* alp  = (const float*)d_in[10];
  const float* phiW = (const float*)d_in[11];
  const float* phib = (const float*)d_in[12];
  const float* rhoW = (const float*)d_in[13];
  const float* rhob = (const float*)d_in[14];
  const int*   src  = (const int*)d_in[15];
  const int*   dst  = (const int*)d_in[16];
  float* out = (float*)d_out;

  int B = in_sizes[0] / (NN*FIN);
  size_t M = (size_t)B*NN;
  size_t BD = (size_t)B*DH;

  float* w = (float*)d_ws;
  size_t p = 0;
  float* nout = w+p; p += 1024;
  float* nin  = w+p; p += 1024;
  int* rp     = (int*)(w+p); p += 1024;
  int* csr_s  = (int*)(w+p); p += 8192;
  int* csr_e  = (int*)(w+p); p += 8192;
  int* csr_d  = (int*)(w+p); p += 8192;
  float* statz = w+p; p += 3*3*BD;           // per layer: [ssum | ssq | zbuf]
  float* ivgP = w+p; p += 3*BD;
  float* pP   = w+p; p += 3*BD;
  unsigned short* wt = (unsigned short*)(w+p); p += 45056;   // 90112 bf16
  float* supn = w+p; p += 24064;             // 3*NE padded
  int2* ec    = (int2*)(w+p); p += (size_t)2*B*NE;
  unsigned short* hpre = (unsigned short*)(w+p); p += M*DH/2;
  unsigned short* agg  = (unsigned short*)(w+p); p += M*DH/2;

  hipMemsetAsync(out, 0, (size_t)out_size*sizeof(float), stream);

  k_topo<<<1, 1024, 0, stream>>>(src, dst, nout, nin, rp, csr_s, csr_e, csr_d);
  k_edge<<<4*B + (3*NE+255)/256, 256, 0, stream>>>(
      ew, sup, nout, nin, csr_s, csr_e, csr_d, ec, supn, B);
  k_misc<<<352 + B*4, 256, 0, stream>>>(W1, W2, W3, phiW, wt, x, gw, AR, out, B);

  const int wt_off[3] = {0, 8192, 24576};
  int nzero4 = (int)(3*BD/4);

  for (int i = 0; i < 3; ++i){
    float* SS = statz + (size_t)i*3*BD;
    if (i == 0){
      k_gath0<<<B*250, 256, 0, stream>>>(x, ec, supn, rp, agg, SS, nzero4);
      k_conv<FIN><<<B*16, 256, 0, stream>>>(agg, wt, hpre, SS, B);
    } else {
      k_gathB<<<B*250, 256, 0, stream>>>(hpre, ec, supn + (size_t)i*NE,
          ivgP + (size_t)(i-1)*BD, pP + (size_t)(i-1)*BD, rp, agg, SS, nzero4);
      k_conv<DH><<<B*16, 256, 0, stream>>>(agg, wt + wt_off[i], hpre, SS, B);
    }
    k_finstats<<<(int)((BD+255)/256), 256, 0, stream>>>(SS, SS + BD,
        alp + i*DH, gam + i*DH, bet + i*DH, ivgP + (size_t)i*BD, pP + (size_t)i*BD, (int)BD);
    k_phi<<<B*16, 256, 0, stream>>>(hpre, wt + 40960 + i*16384,
        ivgP + (size_t)i*BD, pP + (size_t)i*BD, phib + i*DH, gw, AR + (size_t)(i+1)*NN,
        SS + 2*BD, out, 128 + i*192, B);
  }

  k_rho<<<3*B, RD, 0, stream>>>(statz, rhoW, rhob, out, B);
  k_flrelu<<<(B*640+255)/256, 256, 0, stream>>>(out, B*640);
}